// Round 1
// baseline (1653.172 us; speedup 1.0000x reference)
//
#include <hip/hip_runtime.h>
#include <hip/hip_bf16.h>

typedef unsigned int uint;

__device__ __forceinline__ float2 bf2_to_f2(uint u){
  union {unsigned int i; float f;} a,b;
  a.i = (u & 0xffffu) << 16;
  b.i = u & 0xffff0000u;
  return make_float2(a.f, b.f);
}

// ---------------- init / CSR build ----------------

__global__ void k_zero2(int* a, int* b, int n){
  int i = blockIdx.x*blockDim.x + threadIdx.x;
  if (i < n){ a[i]=0; b[i]=0; }
}

// h0 = concat(emb[a], depth_emb[b]) @ projW + projB depends only on (a,b): 9*20=180 combos
__global__ void k_table(const float* __restrict__ emb, const float* __restrict__ demb,
                        const float* __restrict__ W, const float* __restrict__ bias,
                        float* __restrict__ table){
  int d = threadIdx.x;          // 128
  int combo = blockIdx.x;       // 180
  int a = combo/20, b = combo - a*20;
  float acc = bias[d];
  #pragma unroll 8
  for (int i=0;i<32;++i) acc += emb[a*32+i]*W[i*128+d];
  #pragma unroll 8
  for (int i=0;i<32;++i) acc += demb[b*32+i]*W[(32+i)*128+d];
  table[combo*128+d] = acc;
}

__global__ void k_init_h(const int* __restrict__ xn, const float* __restrict__ table,
                         float* __restrict__ h, int n){
  int gid = blockIdx.x*blockDim.x + threadIdx.x;
  if (gid >= n*128) return;
  int node = gid >> 7, d = gid & 127;
  int x0 = xn[2*node];
  int x1 = xn[2*node+1]; x1 = x1<0?0:(x1>19?19:x1);
  h[gid] = table[(x0*20+x1)*128 + d];
}

__global__ void k_count(const int* __restrict__ ei, int* __restrict__ deg, int E, int N){
  int e = blockIdx.x*blockDim.x + threadIdx.x;
  if (e >= E+N) return;
  int dst = (e < E) ? ei[E+e] : (e-E);
  atomicAdd(&deg[dst], 1);
}

__global__ __launch_bounds__(256) void k_scan_block(const int* __restrict__ deg, int* __restrict__ rowstart,
                                                    int* __restrict__ bsum, int n){
  int tid = threadIdx.x;
  int gid = blockIdx.x*256 + tid;
  int lane = tid & 63, wv = tid >> 6;
  int v = (gid < n) ? deg[gid] : 0;
  int x = v;
  #pragma unroll
  for (int off=1; off<64; off<<=1){
    int t = __shfl_up(x, off);
    if (lane >= off) x += t;
  }
  __shared__ int wsum[4], woff[4];
  if (lane==63) wsum[wv] = x;
  __syncthreads();
  if (tid==0){
    int r = 0;
    for (int i=0;i<4;++i){ woff[i]=r; r += wsum[i]; }
    bsum[blockIdx.x] = r;
  }
  __syncthreads();
  if (gid < n) rowstart[gid] = x + woff[wv] - v;   // block-local exclusive
}

__global__ __launch_bounds__(256) void k_scan_sums(int* __restrict__ bsum, int nb){
  int tid = threadIdx.x;
  int lane = tid&63, wv = tid>>6;
  int v = (tid<nb)?bsum[tid]:0;
  int x = v;
  #pragma unroll
  for (int off=1;off<64;off<<=1){ int t=__shfl_up(x,off); if(lane>=off) x+=t; }
  __shared__ int wsum[4], woff[4];
  if (lane==63) wsum[wv]=x;
  __syncthreads();
  if (tid==0){ int r=0; for(int i=0;i<4;++i){woff[i]=r;r+=wsum[i];} }
  __syncthreads();
  if (tid<nb) bsum[tid] = x + woff[wv] - v;        // exclusive block offsets
}

__global__ void k_scan_add(int* __restrict__ rowstart, const int* __restrict__ bsum, int n, int total){
  int gid = blockIdx.x*256 + threadIdx.x;
  if (gid < n) rowstart[gid] += bsum[blockIdx.x];
  if (gid == 0) rowstart[n] = total;
}

__global__ void k_scatter(const int* __restrict__ ei, const int* __restrict__ rowstart,
                          int* __restrict__ cursor, int* __restrict__ csr, int E, int N){
  int e = blockIdx.x*blockDim.x + threadIdx.x;
  if (e >= E+N) return;
  int dst, sv;
  if (e < E){ dst = ei[E+e]; sv = ei[e]; }
  else { dst = e-E; sv = (e-E) | (int)0x80000000; }   // flag self-loop entries
  int pos = rowstart[dst] + atomicAdd(&cursor[dst], 1);
  csr[pos] = sv;
}

// ---------------- GEMM: Y(bf16) = X(f32) @ W(128x128) [+bias] ----------------
// MODE 0: plain, add bias. MODE 1: GAT: no bias; also a_s/a_d head reductions.
template<int MODE>
__global__ __launch_bounds__(256) void k_gemm(const float* __restrict__ X, const float* __restrict__ W,
            const float* __restrict__ bias, __hip_bfloat16* __restrict__ Y,
            const float* __restrict__ att_s, const float* __restrict__ att_d,
            float* __restrict__ a_s, float* __restrict__ a_d, int n){
  __shared__ float wl[128*128];
  __shared__ float xl[256];
  for (int i = threadIdx.x; i < 128*128/4; i += 256)
    reinterpret_cast<float4*>(wl)[i] = reinterpret_cast<const float4*>(W)[i];
  __syncthreads();
  int ty = threadIdx.x >> 7;
  int dd = threadIdx.x & 127;
  int npair = (n+1)>>1;
  for (int pair = blockIdx.x; pair < npair; pair += gridDim.x){
    int n0 = pair*2;
    __syncthreads();
    {
      int ln = n0 + (threadIdx.x>>7);
      xl[threadIdx.x] = (ln < n) ? X[(size_t)ln*128 + (threadIdx.x&127)] : 0.f;
    }
    __syncthreads();
    int node = n0 + ty;
    float acc = 0.f;
    #pragma unroll 16
    for (int i=0;i<128;++i) acc += xl[ty*128 + i] * wl[i*128 + dd];
    if (node < n){
      if (MODE==0){
        Y[(size_t)node*128+dd] = __float2bfloat16(acc + bias[dd]);
      } else {
        Y[(size_t)node*128+dd] = __float2bfloat16(acc);
        float ps = acc * att_s[dd];
        float pd = acc * att_d[dd];
        #pragma unroll
        for (int m=1;m<32;m<<=1){ ps += __shfl_xor(ps,m); pd += __shfl_xor(pd,m); }
        if ((dd&31)==0){
          int hh = dd>>5;
          a_s[(size_t)node*4+hh] = ps;
          a_d[(size_t)node*4+hh] = pd;
        }
      }
    }
  }
}

// ---------------- GAT aggregate: wave per node, online softmax ----------------
__global__ __launch_bounds__(256) void k_gat_agg(const int* __restrict__ rowstart, const int* __restrict__ csr,
              const __hip_bfloat16* __restrict__ hw, const float* __restrict__ a_src,
              const float* __restrict__ a_dst, const float* __restrict__ bias,
              float* __restrict__ h, int n){
  int wv = threadIdx.x >> 6, lane = threadIdx.x & 63;
  int node = blockIdx.x*4 + wv;
  if (node >= n) return;
  int hh = lane >> 4;         // head of dims [2*lane, 2*lane+1]
  int d = lane*2;
  int start = rowstart[node], end = rowstart[node+1];
  float ad = a_dst[(size_t)node*4 + hh];
  float m = -1e30f, s = 0.f, ax = 0.f, ay = 0.f;
  const uint* hw32 = reinterpret_cast<const uint*>(hw);
  for (int p = start; p < end; ++p){
    int src = csr[p] & 0x7fffffff;
    float sc = a_src[(size_t)src*4 + hh] + ad;
    sc = sc >= 0.f ? sc : 0.2f*sc;                     // leaky relu
    float2 hv = bf2_to_f2(hw32[(size_t)src*64 + lane]);
    float mn = fmaxf(m, sc);
    float e1 = __expf(m - mn);
    float e2 = __expf(sc - mn);
    s  = s *e1 + e2;
    ax = ax*e1 + e2*hv.x;
    ay = ay*e1 + e2*hv.y;
    m = mn;
  }
  float inv = 1.f/(s + 1e-16f);
  float ox = ax*inv + bias[d];
  float oy = ay*inv + bias[d+1];
  ox = ox > 0.f ? ox : (__expf(ox)-1.f);              // elu
  oy = oy > 0.f ? oy : (__expf(oy)-1.f);
  float2 hp = *reinterpret_cast<const float2*>(h + (size_t)node*128 + d);
  hp.x += ox; hp.y += oy;
  *reinterpret_cast<float2*>(h + (size_t)node*128 + d) = hp;
}

// ---------------- transformer aggregate: wave per node ----------------
__global__ __launch_bounds__(256) void k_trans_agg(const int* __restrict__ rowstart, const int* __restrict__ csr,
              const __hip_bfloat16* __restrict__ qb, const __hip_bfloat16* __restrict__ kb,
              const __hip_bfloat16* __restrict__ vb, const __hip_bfloat16* __restrict__ skipb,
              float* __restrict__ h, int n){
  int wv = threadIdx.x>>6, lane = threadIdx.x&63;
  int node = blockIdx.x*4+wv;
  if (node>=n) return;
  int d = lane*2;
  const uint* q32 = (const uint*)qb; const uint* k32=(const uint*)kb;
  const uint* v32 = (const uint*)vb; const uint* s32=(const uint*)skipb;
  float2 q2 = bf2_to_f2(q32[(size_t)node*64+lane]);
  int start=rowstart[node], end=rowstart[node+1];
  float m=-1e30f, s=0.f, ax=0.f, ay=0.f;
  for (int p=start;p<end;++p){
    int sv = csr[p];
    if (sv < 0) continue;                 // skip self-loop entries (uniform per wave)
    float2 k2 = bf2_to_f2(k32[(size_t)sv*64+lane]);
    float pr = q2.x*k2.x + q2.y*k2.y;
    pr += __shfl_xor(pr,1); pr += __shfl_xor(pr,2);
    pr += __shfl_xor(pr,4); pr += __shfl_xor(pr,8);   // dot over 32 dims within head
    float sc = pr * 0.17677669529663687f;             // 1/sqrt(32)
    float2 v2 = bf2_to_f2(v32[(size_t)sv*64+lane]);
    float mn = fmaxf(m, sc);
    float e1 = __expf(m-mn), e2 = __expf(sc-mn);
    s  = s *e1 + e2;
    ax = ax*e1 + e2*v2.x;
    ay = ay*e1 + e2*v2.y;
    m = mn;
  }
  float inv = 1.f/(s+1e-16f);
  float2 sk = bf2_to_f2(s32[(size_t)node*64+lane]);
  float tx = ax*inv + sk.x;
  float ty = ay*inv + sk.y;
  tx = tx>0.f?tx:(__expf(tx)-1.f);                    // elu
  ty = ty>0.f?ty:(__expf(ty)-1.f);
  float2 hp = *reinterpret_cast<const float2*>(h+(size_t)node*128+d);
  hp.x += tx; hp.y += ty;
  *reinterpret_cast<float2*>(h+(size_t)node*128+d) = hp;
}

// ---------------- layernorm (in place) ----------------
__global__ __launch_bounds__(256) void k_ln(float* __restrict__ h, const float* __restrict__ g,
                                            const float* __restrict__ b, int n){
  int wv=threadIdx.x>>6, lane=threadIdx.x&63;
  int node = blockIdx.x*4+wv;
  if(node>=n) return;
  int d=lane*2;
  float2 x = *reinterpret_cast<const float2*>(h+(size_t)node*128+d);
  float sm = x.x + x.y;
  #pragma unroll
  for (int m=1;m<64;m<<=1) sm += __shfl_xor(sm,m);
  float mu = sm * (1.f/128.f);
  float dx = x.x-mu, dy = x.y-mu;
  float vs = dx*dx + dy*dy;
  #pragma unroll
  for (int m=1;m<64;m<<=1) vs += __shfl_xor(vs,m);
  float r = rsqrtf(vs*(1.f/128.f) + 1e-5f);
  float2 gg = *reinterpret_cast<const float2*>(g+d);
  float2 bb = *reinterpret_cast<const float2*>(b+d);
  x.x = dx*r*gg.x + bb.x;
  x.y = dy*r*gg.y + bb.y;
  *reinterpret_cast<float2*>(h+(size_t)node*128+d) = x;
}

// ---------------- pooling: binary-search bounds + block per graph ----------------
__global__ void k_gbounds(const int* __restrict__ batch, int* __restrict__ gb, int n, int G){
  int g = blockIdx.x*blockDim.x + threadIdx.x;
  if (g > G) return;
  int lo=0, hi=n;
  while (lo<hi){ int mid=(lo+hi)>>1; if (batch[mid] < g) lo=mid+1; else hi=mid; }
  gb[g] = lo;
}

__global__ void k_pool(const float* __restrict__ hln, const int* __restrict__ gb,
                       float* __restrict__ out, int G){
  int g = blockIdx.x, d = threadIdx.x;   // 128 threads
  int s = gb[g], e = gb[g+1];
  float acc = 0.f;
  for (int i=s;i<e;++i) acc += hln[(size_t)i*128 + d];
  out[(size_t)g*128 + d] = acc / fmaxf((float)(e-s), 1.f);
}

// ---------------- launch ----------------
extern "C" void kernel_launch(void* const* d_in, const int* in_sizes, int n_in,
                              void* d_out, int out_size, void* d_ws, size_t ws_size,
                              hipStream_t stream){
  const int* xn    = (const int*)d_in[0];
  const int* ei    = (const int*)d_in[1];
  const int* batch = (const int*)d_in[2];
  const float* emb  = (const float*)d_in[4];
  const float* demb = (const float*)d_in[5];
  const float* projW= (const float*)d_in[6];
  const float* projB= (const float*)d_in[7];
  const float* gatW = (const float*)d_in[8];
  const float* attS = (const float*)d_in[9];
  const float* attD = (const float*)d_in[10];
  const float* gatB = (const float*)d_in[11];
  const float* Wq = (const float*)d_in[12];
  const float* bq = (const float*)d_in[13];
  const float* Wk = (const float*)d_in[14];
  const float* bk = (const float*)d_in[15];
  const float* Wv = (const float*)d_in[16];
  const float* bv = (const float*)d_in[17];
  const float* Wsk= (const float*)d_in[18];
  const float* bsk= (const float*)d_in[19];
  const float* lng= (const float*)d_in[20];
  const float* lnb= (const float*)d_in[21];
  float* out = (float*)d_out;

  int N = in_sizes[0]/2;
  int E = in_sizes[1]/2;
  int G = out_size/128;
  int T = E + N;

  char* w = (char*)d_ws;
  size_t off = 0;
  auto alloc = [&](size_t bytes)->char*{ char* p = w+off; off += (bytes + 255) & ~(size_t)255; return p; };
  float* h            = (float*)alloc((size_t)N*128*4);
  __hip_bfloat16* hw  = (__hip_bfloat16*)alloc((size_t)N*128*2);
  __hip_bfloat16* qb  = (__hip_bfloat16*)alloc((size_t)N*128*2);
  __hip_bfloat16* kb  = (__hip_bfloat16*)alloc((size_t)N*128*2);
  __hip_bfloat16* vb  = (__hip_bfloat16*)alloc((size_t)N*128*2);
  __hip_bfloat16* skb = (__hip_bfloat16*)alloc((size_t)N*128*2);
  float* a_s  = (float*)alloc((size_t)N*4*4);
  float* a_d  = (float*)alloc((size_t)N*4*4);
  int* deg    = (int*)alloc((size_t)N*4);
  int* cursor = (int*)alloc((size_t)N*4);
  int* rowstart=(int*)alloc((size_t)(N+1)*4);
  int* csr    = (int*)alloc((size_t)T*4);
  int* bsum   = (int*)alloc(4096);
  int* gb     = (int*)alloc((size_t)(G+1)*4);
  float* table= (float*)alloc(180*128*4);
  (void)ws_size; (void)n_in;

  int nb = (N+255)/256;

  k_zero2<<<(N+255)/256,256,0,stream>>>(deg, cursor, N);
  k_table<<<180,128,0,stream>>>(emb, demb, projW, projB, table);
  k_init_h<<<(N*128+255)/256,256,0,stream>>>(xn, table, h, N);
  k_count<<<(T+255)/256,256,0,stream>>>(ei, deg, E, N);
  k_scan_block<<<nb,256,0,stream>>>(deg, rowstart, bsum, N);
  k_scan_sums<<<1,256,0,stream>>>(bsum, nb);
  k_scan_add<<<nb,256,0,stream>>>(rowstart, bsum, N, T);
  k_scatter<<<(T+255)/256,256,0,stream>>>(ei, rowstart, cursor, csr, E, N);

  for (int l=0;l<3;++l){
    k_gemm<1><<<512,256,0,stream>>>(h, gatW + (size_t)l*128*128, nullptr, hw,
                                    attS + l*128, attD + l*128, a_s, a_d, N);
    k_gat_agg<<<(N+3)/4,256,0,stream>>>(rowstart, csr, hw, a_s, a_d, gatB + l*128, h, N);
  }

  k_gemm<0><<<512,256,0,stream>>>(h, Wq,  bq,  qb,  nullptr,nullptr,nullptr,nullptr, N);
  k_gemm<0><<<512,256,0,stream>>>(h, Wk,  bk,  kb,  nullptr,nullptr,nullptr,nullptr, N);
  k_gemm<0><<<512,256,0,stream>>>(h, Wv,  bv,  vb,  nullptr,nullptr,nullptr,nullptr, N);
  k_gemm<0><<<512,256,0,stream>>>(h, Wsk, bsk, skb, nullptr,nullptr,nullptr,nullptr, N);
  k_trans_agg<<<(N+3)/4,256,0,stream>>>(rowstart, csr, qb, kb, vb, skb, h, N);

  k_ln<<<(N+3)/4,256,0,stream>>>(h, lng, lnb, N);
  k_gbounds<<<(G+256)/256,256,0,stream>>>(batch, gb, N, G);
  k_pool<<<G,128,0,stream>>>(h, gb, out, G);
}

// Round 2
// 769.779 us; speedup vs baseline: 2.1476x; 2.1476x over previous
//
#include <hip/hip_runtime.h>
#include <hip/hip_bf16.h>

typedef unsigned int uint;
typedef unsigned short ushort;
typedef __attribute__((ext_vector_type(8))) short bf16x8;
typedef __attribute__((ext_vector_type(4))) float f32x4;

__device__ __forceinline__ float2 bf2_to_f2(uint u){
  union {unsigned int i; float f;} a,b;
  a.i = (u & 0xffffu) << 16;
  b.i = u & 0xffff0000u;
  return make_float2(a.f, b.f);
}
__device__ __forceinline__ ushort bf16bits(float f){
  union{ __hip_bfloat16 h; ushort u;} x; x.h = __float2bfloat16(f); return x.u;
}
__device__ __forceinline__ uint pack_bf2(float x, float y){
  return ((uint)bf16bits(y)<<16) | (uint)bf16bits(x);
}

// ---------------- init / CSR build ----------------

__global__ void k_zero2(int* a, int* b, int n){
  int i = blockIdx.x*blockDim.x + threadIdx.x;
  if (i < n){ a[i]=0; b[i]=0; }
}

// h0 = concat(emb[a], depth_emb[b]) @ projW + projB depends only on (a,b): 9*20=180 combos
__global__ void k_table(const float* __restrict__ emb, const float* __restrict__ demb,
                        const float* __restrict__ W, const float* __restrict__ bias,
                        float* __restrict__ table){
  int d = threadIdx.x;          // 128
  int combo = blockIdx.x;       // 180
  int a = combo/20, b = combo - a*20;
  float acc = bias[d];
  #pragma unroll 8
  for (int i=0;i<32;++i) acc += emb[a*32+i]*W[i*128+d];
  #pragma unroll 8
  for (int i=0;i<32;++i) acc += demb[b*32+i]*W[(32+i)*128+d];
  table[combo*128+d] = acc;
}

__global__ void k_init_h(const int* __restrict__ xn, const float* __restrict__ table,
                         float* __restrict__ h, ushort* __restrict__ hb, int n){
  int gid = blockIdx.x*blockDim.x + threadIdx.x;
  if (gid >= n*64) return;
  int node = gid >> 6, lp = gid & 63;
  int x0 = xn[2*node];
  int x1 = xn[2*node+1]; x1 = x1<0?0:(x1>19?19:x1);
  const float* tr = table + (size_t)(x0*20+x1)*128 + lp*2;
  float a = tr[0], b = tr[1];
  float2 v = make_float2(a,b);
  *reinterpret_cast<float2*>(h + (size_t)node*128 + lp*2) = v;
  reinterpret_cast<uint*>(hb)[(size_t)node*64 + lp] = pack_bf2(a,b);
}

__global__ void k_count(const int* __restrict__ ei, int* __restrict__ deg, int E, int N){
  int e = blockIdx.x*blockDim.x + threadIdx.x;
  if (e >= E+N) return;
  int dst = (e < E) ? ei[E+e] : (e-E);
  atomicAdd(&deg[dst], 1);
}

__global__ __launch_bounds__(256) void k_scan_block(const int* __restrict__ deg, int* __restrict__ rowstart,
                                                    int* __restrict__ bsum, int n){
  int tid = threadIdx.x;
  int gid = blockIdx.x*256 + tid;
  int lane = tid & 63, wv = tid >> 6;
  int v = (gid < n) ? deg[gid] : 0;
  int x = v;
  #pragma unroll
  for (int off=1; off<64; off<<=1){
    int t = __shfl_up(x, off);
    if (lane >= off) x += t;
  }
  __shared__ int wsum[4], woff[4];
  if (lane==63) wsum[wv] = x;
  __syncthreads();
  if (tid==0){
    int r = 0;
    for (int i=0;i<4;++i){ woff[i]=r; r += wsum[i]; }
    bsum[blockIdx.x] = r;
  }
  __syncthreads();
  if (gid < n) rowstart[gid] = x + woff[wv] - v;
}

__global__ __launch_bounds__(256) void k_scan_sums(int* __restrict__ bsum, int nb){
  int tid = threadIdx.x;
  int lane = tid&63, wv = tid>>6;
  int v = (tid<nb)?bsum[tid]:0;
  int x = v;
  #pragma unroll
  for (int off=1;off<64;off<<=1){ int t=__shfl_up(x,off); if(lane>=off) x+=t; }
  __shared__ int wsum[4], woff[4];
  if (lane==63) wsum[wv]=x;
  __syncthreads();
  if (tid==0){ int r=0; for(int i=0;i<4;++i){woff[i]=r;r+=wsum[i];} }
  __syncthreads();
  if (tid<nb) bsum[tid] = x + woff[wv] - v;
}

__global__ void k_scan_add(int* __restrict__ rowstart, const int* __restrict__ bsum, int n, int total){
  int gid = blockIdx.x*256 + threadIdx.x;
  if (gid < n) rowstart[gid] += bsum[blockIdx.x];
  if (gid == 0) rowstart[n] = total;
}

__global__ void k_scatter(const int* __restrict__ ei, const int* __restrict__ rowstart,
                          int* __restrict__ cursor, int* __restrict__ csr, int E, int N){
  int e = blockIdx.x*blockDim.x + threadIdx.x;
  if (e >= E+N) return;
  int dst, sv;
  if (e < E){ dst = ei[E+e]; sv = ei[e]; }
  else { dst = e-E; sv = (e-E) | (int)0x80000000; }   // flag self-loop entries
  int pos = rowstart[dst] + atomicAdd(&cursor[dst], 1);
  csr[pos] = sv;
}

// ---------------- weight prep (bf16, transposed, permuted) ----------------

// wt[l][c][k] = bf16(gatW[l][k][c])
__global__ void k_prep_wt_gat(const float* __restrict__ gatW, ushort* __restrict__ wt){
  int i = blockIdx.x*256 + threadIdx.x;   // < 3*128*128
  int l = i >> 14, rem = i & 16383, c = rem >> 7, k = rem & 127;
  wt[i] = bf16bits(gatW[l*16384 + k*128 + c]);
}

// fused q|kv-interleaved|skip: out col c in [0,512); wt[c][k]; bias[c] (q scaled by 1/sqrt(32))
__global__ void k_prep_wt_qkvs(const float* __restrict__ Wq, const float* __restrict__ Wk,
                               const float* __restrict__ Wv, const float* __restrict__ Ws,
                               const float* __restrict__ bq, const float* __restrict__ bk,
                               const float* __restrict__ bv, const float* __restrict__ bs,
                               ushort* __restrict__ wt, float* __restrict__ bias){
  int i = blockIdx.x*256 + threadIdx.x;   // < 512*128
  int c = i >> 7, k = i & 127;
  const float* W; const float* B; int sc; float scale = 1.f;
  if (c < 128){ W = Wq; B = bq; sc = c; scale = 0.17677669529663687f; }
  else if (c < 384){
    int idx = c - 128; int l = idx >> 2, wn = idx & 3;
    if (wn < 2){ W = Wk; B = bk; sc = l*2 + wn; }
    else       { W = Wv; B = bv; sc = l*2 + wn - 2; }
  } else { W = Ws; B = bs; sc = c - 384; }
  wt[c*128 + k] = bf16bits(W[k*128 + sc] * scale);
  if (k == 0) bias[c] = B[sc] * scale;
}

// ---------------- MFMA GEMM: Y(bf16 N x CT*128) = X(bf16 N x 128) @ Wt^T + bias ----------------
template<int CT>
__global__ __launch_bounds__(256) void k_gemm_mfma(const ushort* __restrict__ X,
        const ushort* __restrict__ Wt, const float* __restrict__ bias,
        ushort* __restrict__ Y, int n){
  __shared__ ushort wl[128*136];            // 128 cols x 128 k, stride 136 (pad 8)
  const int t = threadIdx.x;
  const int w = t >> 6, lane = t & 63;
  const int cl = lane & 15, khi = lane >> 4;
  const int rbase = blockIdx.x*64;
  const int C = CT*128;

  int arow = rbase + w*16 + cl; if (arow >= n) arow = n-1;
  const bf16x8* Xr = reinterpret_cast<const bf16x8*>(X + (size_t)arow*128);
  bf16x8 a0 = Xr[0+khi], a1 = Xr[4+khi], a2 = Xr[8+khi], a3 = Xr[12+khi];

  for (int ct=0; ct<CT; ++ct){
    __syncthreads();
    {
      int col = t >> 1, k0 = (t & 1)*64;
      const bf16x8* src = reinterpret_cast<const bf16x8*>(Wt + ((size_t)(ct*128+col))*128 + k0);
      bf16x8* dst = reinterpret_cast<bf16x8*>(wl + col*136 + k0);
      #pragma unroll
      for (int i=0;i<8;++i) dst[i] = src[i];
    }
    __syncthreads();

    f32x4 acc[8];
    #pragma unroll
    for (int cf=0;cf<8;++cf) acc[cf] = f32x4{0.f,0.f,0.f,0.f};

    #pragma unroll
    for (int ks=0; ks<4; ++ks){
      bf16x8 av = (ks==0)?a0:(ks==1)?a1:(ks==2)?a2:a3;
      #pragma unroll
      for (int cf=0; cf<8; ++cf){
        bf16x8 bv = *reinterpret_cast<const bf16x8*>(wl + (cf*16+cl)*136 + ks*32 + khi*8);
        acc[cf] = __builtin_amdgcn_mfma_f32_16x16x32_bf16(av, bv, acc[cf], 0, 0, 0);
      }
    }

    #pragma unroll
    for (int j=0;j<4;++j){
      int node = rbase + w*16 + khi*4 + j;
      if (node < n){
        ushort* yr = Y + (size_t)node*C + ct*128 + cl;
        #pragma unroll
        for (int cf=0;cf<8;++cf){
          float v = acc[cf][j] + (bias ? bias[ct*128 + cf*16 + cl] : 0.f);
          yr[cf*16] = bf16bits(v);
        }
      }
    }
  }
}

// ---------------- per-layer attention scalars: a_s/a_d[node][h] ----------------
__global__ __launch_bounds__(256) void k_att(const ushort* __restrict__ hw,
        const float* __restrict__ attS, const float* __restrict__ attD,
        float* __restrict__ a_s, float* __restrict__ a_d, int n){
  int wv = threadIdx.x>>6, lane = threadIdx.x&63;
  int node = blockIdx.x*4 + wv; if (node>=n) return;
  float2 f = bf2_to_f2(reinterpret_cast<const uint*>(hw)[(size_t)node*64 + lane]);
  float2 as = *reinterpret_cast<const float2*>(attS + 2*lane);
  float2 ad = *reinterpret_cast<const float2*>(attD + 2*lane);
  float ps = f.x*as.x + f.y*as.y;
  float pd = f.x*ad.x + f.y*ad.y;
  #pragma unroll
  for (int m=1;m<16;m<<=1){ ps += __shfl_xor(ps,m); pd += __shfl_xor(pd,m); }
  if ((lane&15)==0){
    a_s[(size_t)node*4 + (lane>>4)] = ps;
    a_d[(size_t)node*4 + (lane>>4)] = pd;
  }
}

// ---------------- GAT aggregate: wave per node, direct-exp softmax ----------------
__global__ __launch_bounds__(256) void k_gat_agg(const int* __restrict__ rowstart, const int* __restrict__ csr,
              const ushort* __restrict__ hw, const float* __restrict__ a_src,
              const float* __restrict__ a_dst, const float* __restrict__ bias,
              float* __restrict__ h, ushort* __restrict__ hb, int n){
  int wv = threadIdx.x >> 6, lane = threadIdx.x & 63;
  int node = blockIdx.x*4 + wv;
  if (node >= n) return;
  int hh = lane >> 4;
  int d = lane*2;
  int start = rowstart[node], end = rowstart[node+1];
  float ad = a_dst[(size_t)node*4 + hh];
  float s = 0.f, ax = 0.f, ay = 0.f;
  const uint* hw32 = reinterpret_cast<const uint*>(hw);
  int p = start;
  for (; p+1 < end; p += 2){
    int e0 = csr[p] & 0x7fffffff;
    int e1 = csr[p+1] & 0x7fffffff;
    float as0 = a_src[(size_t)e0*4 + hh];
    float as1 = a_src[(size_t)e1*4 + hh];
    uint u0 = hw32[(size_t)e0*64 + lane];
    uint u1 = hw32[(size_t)e1*64 + lane];
    float sc0 = as0 + ad; sc0 = sc0 >= 0.f ? sc0 : 0.2f*sc0;
    float sc1 = as1 + ad; sc1 = sc1 >= 0.f ? sc1 : 0.2f*sc1;
    float w0 = __expf(fminf(sc0, 30.f));
    float w1 = __expf(fminf(sc1, 30.f));
    float2 f0 = bf2_to_f2(u0), f1 = bf2_to_f2(u1);
    s  += w0 + w1;
    ax += w0*f0.x + w1*f1.x;
    ay += w0*f0.y + w1*f1.y;
  }
  if (p < end){
    int e0 = csr[p] & 0x7fffffff;
    float sc0 = a_src[(size_t)e0*4 + hh] + ad; sc0 = sc0 >= 0.f ? sc0 : 0.2f*sc0;
    float w0 = __expf(fminf(sc0, 30.f));
    float2 f0 = bf2_to_f2(hw32[(size_t)e0*64 + lane]);
    s += w0; ax += w0*f0.x; ay += w0*f0.y;
  }
  float inv = 1.f/(s + 1e-16f);
  float ox = ax*inv + bias[d];
  float oy = ay*inv + bias[d+1];
  ox = ox > 0.f ? ox : (__expf(ox)-1.f);
  oy = oy > 0.f ? oy : (__expf(oy)-1.f);
  float2 hp = *reinterpret_cast<const float2*>(h + (size_t)node*128 + d);
  hp.x += ox; hp.y += oy;
  *reinterpret_cast<float2*>(h + (size_t)node*128 + d) = hp;
  reinterpret_cast<uint*>(hb)[(size_t)node*64 + lane] = pack_bf2(hp.x, hp.y);
}

// ---------------- transformer aggregate (q|kv|skip fused buffer) ----------------
__global__ __launch_bounds__(256) void k_trans_agg(const int* __restrict__ rowstart, const int* __restrict__ csr,
              const ushort* __restrict__ yb, float* __restrict__ h, int n){
  int wv = threadIdx.x>>6, lane = threadIdx.x&63;
  int node = blockIdx.x*4 + wv;
  if (node >= n) return;
  const uint*  y32 = reinterpret_cast<const uint*>(yb);    // 256 u32 per node row
  const uint2* kvp = reinterpret_cast<const uint2*>(yb);   // 128 uint2 per node row; kv at +32
  float2 q2 = bf2_to_f2(y32[(size_t)node*256 + lane]);     // q already scaled by 1/sqrt(32)
  int start = rowstart[node], end = rowstart[node+1];
  float s = 0.f, ax = 0.f, ay = 0.f;
  int p = start;
  for (; p+1 < end; p += 2){
    int sv0 = csr[p], sv1 = csr[p+1];
    int s0 = sv0 & 0x7fffffff, s1 = sv1 & 0x7fffffff;
    uint2 kv0 = kvp[(size_t)s0*128 + 32 + lane];
    uint2 kv1 = kvp[(size_t)s1*128 + 32 + lane];
    float2 k0 = bf2_to_f2(kv0.x), v0 = bf2_to_f2(kv0.y);
    float2 k1 = bf2_to_f2(kv1.x), v1 = bf2_to_f2(kv1.y);
    float pr0 = q2.x*k0.x + q2.y*k0.y;
    float pr1 = q2.x*k1.x + q2.y*k1.y;
    pr0 += __shfl_xor(pr0,1); pr1 += __shfl_xor(pr1,1);
    pr0 += __shfl_xor(pr0,2); pr1 += __shfl_xor(pr1,2);
    pr0 += __shfl_xor(pr0,4); pr1 += __shfl_xor(pr1,4);
    pr0 += __shfl_xor(pr0,8); pr1 += __shfl_xor(pr1,8);
    float w0 = (sv0 >= 0) ? __expf(fminf(pr0, 30.f)) : 0.f;   // self-loop => weight 0
    float w1 = (sv1 >= 0) ? __expf(fminf(pr1, 30.f)) : 0.f;
    s  += w0 + w1;
    ax += w0*v0.x + w1*v1.x;
    ay += w0*v0.y + w1*v1.y;
  }
  if (p < end){
    int sv0 = csr[p];
    int s0 = sv0 & 0x7fffffff;
    uint2 kv0 = kvp[(size_t)s0*128 + 32 + lane];
    float2 k0 = bf2_to_f2(kv0.x), v0 = bf2_to_f2(kv0.y);
    float pr0 = q2.x*k0.x + q2.y*k0.y;
    pr0 += __shfl_xor(pr0,1); pr0 += __shfl_xor(pr0,2);
    pr0 += __shfl_xor(pr0,4); pr0 += __shfl_xor(pr0,8);
    float w0 = (sv0 >= 0) ? __expf(fminf(pr0, 30.f)) : 0.f;
    s += w0; ax += w0*v0.x; ay += w0*v0.y;
  }
  float inv = 1.f/(s + 1e-16f);
  float2 sk = bf2_to_f2(y32[(size_t)node*256 + 192 + lane]);
  float tx = ax*inv + sk.x;
  float ty = ay*inv + sk.y;
  tx = tx>0.f?tx:(__expf(tx)-1.f);
  ty = ty>0.f?ty:(__expf(ty)-1.f);
  int d = lane*2;
  float2 hp = *reinterpret_cast<const float2*>(h + (size_t)node*128 + d);
  hp.x += tx; hp.y += ty;
  *reinterpret_cast<float2*>(h + (size_t)node*128 + d) = hp;
}

// ---------------- layernorm (in place) ----------------
__global__ __launch_bounds__(256) void k_ln(float* __restrict__ h, const float* __restrict__ g,
                                            const float* __restrict__ b, int n){
  int wv=threadIdx.x>>6, lane=threadIdx.x&63;
  int node = blockIdx.x*4+wv;
  if(node>=n) return;
  int d=lane*2;
  float2 x = *reinterpret_cast<const float2*>(h+(size_t)node*128+d);
  float sm = x.x + x.y;
  #pragma unroll
  for (int m=1;m<64;m<<=1) sm += __shfl_xor(sm,m);
  float mu = sm * (1.f/128.f);
  float dx = x.x-mu, dy = x.y-mu;
  float vs = dx*dx + dy*dy;
  #pragma unroll
  for (int m=1;m<64;m<<=1) vs += __shfl_xor(vs,m);
  float r = rsqrtf(vs*(1.f/128.f) + 1e-5f);
  float2 gg = *reinterpret_cast<const float2*>(g+d);
  float2 bb = *reinterpret_cast<const float2*>(b+d);
  x.x = dx*r*gg.x + bb.x;
  x.y = dy*r*gg.y + bb.y;
  *reinterpret_cast<float2*>(h+(size_t)node*128+d) = x;
}

// ---------------- pooling ----------------
__global__ void k_gbounds(const int* __restrict__ batch, int* __restrict__ gb, int n, int G){
  int g = blockIdx.x*blockDim.x + threadIdx.x;
  if (g > G) return;
  int lo=0, hi=n;
  while (lo<hi){ int mid=(lo+hi)>>1; if (batch[mid] < g) lo=mid+1; else hi=mid; }
  gb[g] = lo;
}

__global__ void k_pool(const float* __restrict__ hln, const int* __restrict__ gb,
                       float* __restrict__ out, int G){
  int g = blockIdx.x, d = threadIdx.x;   // 128 threads
  int s = gb[g], e = gb[g+1];
  float acc = 0.f;
  for (int i=s;i<e;++i) acc += hln[(size_t)i*128 + d];
  out[(size_t)g*128 + d] = acc / fmaxf((float)(e-s), 1.f);
}

// ---------------- launch ----------------
extern "C" void kernel_launch(void* const* d_in, const int* in_sizes, int n_in,
                              void* d_out, int out_size, void* d_ws, size_t ws_size,
                              hipStream_t stream){
  const int* xn    = (const int*)d_in[0];
  const int* ei    = (const int*)d_in[1];
  const int* batch = (const int*)d_in[2];
  const float* emb  = (const float*)d_in[4];
  const float* demb = (const float*)d_in[5];
  const float* projW= (const float*)d_in[6];
  const float* projB= (const float*)d_in[7];
  const float* gatW = (const float*)d_in[8];
  const float* attS = (const float*)d_in[9];
  const float* attD = (const float*)d_in[10];
  const float* gatB = (const float*)d_in[11];
  const float* Wq = (const float*)d_in[12];
  const float* bq = (const float*)d_in[13];
  const float* Wk = (const float*)d_in[14];
  const float* bk = (const float*)d_in[15];
  const float* Wv = (const float*)d_in[16];
  const float* bv = (const float*)d_in[17];
  const float* Wsk= (const float*)d_in[18];
  const float* bsk= (const float*)d_in[19];
  const float* lng= (const float*)d_in[20];
  const float* lnb= (const float*)d_in[21];
  float* out = (float*)d_out;

  int N = in_sizes[0]/2;
  int E = in_sizes[1]/2;
  int G = out_size/128;
  int T = E + N;

  char* w = (char*)d_ws;
  size_t off = 0;
  auto alloc = [&](size_t bytes)->char*{ char* p = w+off; off += (bytes + 255) & ~(size_t)255; return p; };
  float*  h    = (float*) alloc((size_t)N*128*4);
  ushort* hb   = (ushort*)alloc((size_t)N*128*2);
  ushort* ybuf = (ushort*)alloc((size_t)N*512*2);   // hw aliases first 1/4 during GAT phase
  ushort* hw   = ybuf;
  float* a_s  = (float*)alloc((size_t)N*4*4);
  float* a_d  = (float*)alloc((size_t)N*4*4);
  int* deg    = (int*)alloc((size_t)N*4);
  int* cursor = (int*)alloc((size_t)N*4);
  int* rowstart=(int*)alloc((size_t)(N+1)*4);
  int* csr    = (int*)alloc((size_t)T*4);
  int* bsum   = (int*)alloc(4096);
  int* gb     = (int*)alloc((size_t)(G+1)*4);
  float* table= (float*)alloc(180*128*4);
  ushort* wt_gat  = (ushort*)alloc((size_t)3*128*128*2);
  ushort* wt_qkvs = (ushort*)alloc((size_t)512*128*2);
  float* bias512  = (float*)alloc(512*4);
  (void)ws_size; (void)n_in;

  int nb = (N+255)/256;

  k_zero2<<<(N+255)/256,256,0,stream>>>(deg, cursor, N);
  k_table<<<180,128,0,stream>>>(emb, demb, projW, projB, table);
  k_init_h<<<(N*64+255)/256,256,0,stream>>>(xn, table, h, hb, N);
  k_count<<<(T+255)/256,256,0,stream>>>(ei, deg, E, N);
  k_scan_block<<<nb,256,0,stream>>>(deg, rowstart, bsum, N);
  k_scan_sums<<<1,256,0,stream>>>(bsum, nb);
  k_scan_add<<<nb,256,0,stream>>>(rowstart, bsum, N, T);
  k_scatter<<<(T+255)/256,256,0,stream>>>(ei, rowstart, cursor, csr, E, N);
  k_prep_wt_gat<<<192,256,0,stream>>>(gatW, wt_gat);
  k_prep_wt_qkvs<<<256,256,0,stream>>>(Wq, Wk, Wv, Wsk, bq, bk, bv, bsk, wt_qkvs, bias512);

  int gemm_grid = (N+63)/64;
  for (int l=0;l<3;++l){
    k_gemm_mfma<1><<<gemm_grid,256,0,stream>>>(hb, wt_gat + (size_t)l*16384, nullptr, hw, N);
    k_att<<<(N+3)/4,256,0,stream>>>(hw, attS + l*128, attD + l*128, a_s, a_d, N);
    k_gat_agg<<<(N+3)/4,256,0,stream>>>(rowstart, csr, hw, a_s, a_d, gatB + l*128, h, hb, N);
  }

  k_gemm_mfma<4><<<gemm_grid,256,0,stream>>>(hb, wt_qkvs, bias512, ybuf, N);
  k_trans_agg<<<(N+3)/4,256,0,stream>>>(rowstart, csr, ybuf, h, N);

  k_ln<<<(N+3)/4,256,0,stream>>>(h, lng, lnb, N);
  k_gbounds<<<(G+256)/256,256,0,stream>>>(batch, gb, N, G);
  k_pool<<<G,128,0,stream>>>(h, gb, out, G);
}

// Round 3
// 695.127 us; speedup vs baseline: 2.3782x; 1.1074x over previous
//
#include <hip/hip_runtime.h>
#include <hip/hip_bf16.h>

typedef unsigned int uint;
typedef unsigned short ushort;
typedef __attribute__((ext_vector_type(8))) short bf16x8;
typedef __attribute__((ext_vector_type(4))) float f32x4;

__device__ __forceinline__ float2 bf2_to_f2(uint u){
  union {unsigned int i; float f;} a,b;
  a.i = (u & 0xffffu) << 16;
  b.i = u & 0xffff0000u;
  return make_float2(a.f, b.f);
}
__device__ __forceinline__ ushort bf16bits(float f){
  union{ __hip_bfloat16 h; ushort u;} x; x.h = __float2bfloat16(f); return x.u;
}
__device__ __forceinline__ uint pack_bf2(float x, float y){
  return ((uint)bf16bits(y)<<16) | (uint)bf16bits(x);
}
// e4m3fn (OCP) pair decode; result carries the encoder's x16 scale (fold 1/16 downstream)
__device__ __forceinline__ float2 fp8x2_to_f2(uint us){
  uint b0 = us & 0xffu, b1 = (us >> 8) & 0xffu;
  union {uint i; float f;} x, y;
  x.i = ((b0 & 0x80u) << 24) | ((b0 & 0x7fu) << 20);
  y.i = ((b1 & 0x80u) << 24) | ((b1 & 0x7fu) << 20);
  return make_float2(x.f * 0x1p120f, y.f * 0x1p120f);
}

// ---------------- init / CSR build ----------------

__global__ void k_zero2(int* a, int* b, int n){
  int i = blockIdx.x*blockDim.x + threadIdx.x;
  if (i < n){ a[i]=0; b[i]=0; }
}

__global__ void k_table(const float* __restrict__ emb, const float* __restrict__ demb,
                        const float* __restrict__ W, const float* __restrict__ bias,
                        float* __restrict__ table){
  int d = threadIdx.x;          // 128
  int combo = blockIdx.x;       // 180
  int a = combo/20, b = combo - a*20;
  float acc = bias[d];
  #pragma unroll 8
  for (int i=0;i<32;++i) acc += emb[a*32+i]*W[i*128+d];
  #pragma unroll 8
  for (int i=0;i<32;++i) acc += demb[b*32+i]*W[(32+i)*128+d];
  table[combo*128+d] = acc;
}

__global__ void k_init_h(const int* __restrict__ xn, const float* __restrict__ table,
                         float* __restrict__ h, ushort* __restrict__ hb, int n){
  int gid = blockIdx.x*blockDim.x + threadIdx.x;
  if (gid >= n*64) return;
  int node = gid >> 6, lp = gid & 63;
  int x0 = xn[2*node];
  int x1 = xn[2*node+1]; x1 = x1<0?0:(x1>19?19:x1);
  const float* tr = table + (size_t)(x0*20+x1)*128 + lp*2;
  float a = tr[0], b = tr[1];
  *reinterpret_cast<float2*>(h + (size_t)node*128 + lp*2) = make_float2(a,b);
  reinterpret_cast<uint*>(hb)[(size_t)node*64 + lp] = pack_bf2(a,b);
}

__global__ void k_count(const int* __restrict__ ei, int* __restrict__ deg, int E, int N){
  int e = blockIdx.x*blockDim.x + threadIdx.x;
  if (e >= E+N) return;
  int dst = (e < E) ? ei[E+e] : (e-E);
  atomicAdd(&deg[dst], 1);
}

__global__ __launch_bounds__(256) void k_scan_block(const int* __restrict__ deg, int* __restrict__ rowstart,
                                                    int* __restrict__ bsum, int n){
  int tid = threadIdx.x;
  int gid = blockIdx.x*256 + tid;
  int lane = tid & 63, wv = tid >> 6;
  int v = (gid < n) ? deg[gid] : 0;
  int x = v;
  #pragma unroll
  for (int off=1; off<64; off<<=1){
    int t = __shfl_up(x, off);
    if (lane >= off) x += t;
  }
  __shared__ int wsum[4], woff[4];
  if (lane==63) wsum[wv] = x;
  __syncthreads();
  if (tid==0){
    int r = 0;
    for (int i=0;i<4;++i){ woff[i]=r; r += wsum[i]; }
    bsum[blockIdx.x] = r;
  }
  __syncthreads();
  if (gid < n) rowstart[gid] = x + woff[wv] - v;
}

__global__ __launch_bounds__(256) void k_scan_sums(int* __restrict__ bsum, int nb){
  int tid = threadIdx.x;
  int lane = tid&63, wv = tid>>6;
  int v = (tid<nb)?bsum[tid]:0;
  int x = v;
  #pragma unroll
  for (int off=1;off<64;off<<=1){ int t=__shfl_up(x,off); if(lane>=off) x+=t; }
  __shared__ int wsum[4], woff[4];
  if (lane==63) wsum[wv]=x;
  __syncthreads();
  if (tid==0){ int r=0; for(int i=0;i<4;++i){woff[i]=r;r+=wsum[i];} }
  __syncthreads();
  if (tid<nb) bsum[tid] = x + woff[wv] - v;
}

__global__ void k_scan_add(int* __restrict__ rowstart, const int* __restrict__ bsum, int n, int total){
  int gid = blockIdx.x*256 + threadIdx.x;
  if (gid < n) rowstart[gid] += bsum[blockIdx.x];
  if (gid == 0) rowstart[n] = total;
}

__global__ void k_scatter(const int* __restrict__ ei, const int* __restrict__ rowstart,
                          int* __restrict__ cursor, int* __restrict__ csr, int E, int N){
  int e = blockIdx.x*blockDim.x + threadIdx.x;
  if (e >= E+N) return;
  int dst, sv;
  if (e < E){ dst = ei[E+e]; sv = ei[e]; }
  else { dst = e-E; sv = (e-E) | (int)0x80000000; }   // flag self-loop entries
  int pos = rowstart[dst] + atomicAdd(&cursor[dst], 1);
  csr[pos] = sv;
}

// ---------------- weight prep ----------------

__global__ void k_prep_wt_gat(const float* __restrict__ gatW, ushort* __restrict__ wt){
  int i = blockIdx.x*256 + threadIdx.x;   // < 3*128*128
  int l = i >> 14, rem = i & 16383, c = rem >> 7, k = rem & 127;
  wt[i] = bf16bits(gatW[l*16384 + k*128 + c]);
}

__global__ void k_prep_wt_qkvs(const float* __restrict__ Wq, const float* __restrict__ Wk,
                               const float* __restrict__ Wv, const float* __restrict__ Ws,
                               const float* __restrict__ bq, const float* __restrict__ bk,
                               const float* __restrict__ bv, const float* __restrict__ bs,
                               ushort* __restrict__ wt, float* __restrict__ bias){
  int i = blockIdx.x*256 + threadIdx.x;   // < 512*128
  int c = i >> 7, k = i & 127;
  const float* W; const float* B; int sc; float scale = 1.f;
  if (c < 128){ W = Wq; B = bq; sc = c; scale = 0.17677669529663687f; }
  else if (c < 384){
    int idx = c - 128; int l = idx >> 2, wn = idx & 3;
    if (wn < 2){ W = Wk; B = bk; sc = l*2 + wn; }
    else       { W = Wv; B = bv; sc = l*2 + wn - 2; }
  } else { W = Ws; B = bs; sc = c - 384; }
  wt[c*128 + k] = bf16bits(W[k*128 + sc] * scale);
  if (k == 0) bias[c] = B[sc] * scale;
}

// ---------------- MFMA GEMM ----------------
// OUTFP8=0: Y bf16 canonical cols, + bias. OUTFP8=1: Y fp8 (x16 scale), permuted
// layout: byte pos cl*8+cf holds col cf*16+cl (lane writes one dwordx2 per row).
template<int CT, int OUTFP8>
__global__ __launch_bounds__(256) void k_gemm_mfma(const ushort* __restrict__ X,
        const ushort* __restrict__ Wt, const float* __restrict__ bias,
        void* __restrict__ Yv, int n){
  __shared__ ushort wl[128*136];
  const int t = threadIdx.x;
  const int w = t >> 6, lane = t & 63;
  const int cl = lane & 15, khi = lane >> 4;
  const int rbase = blockIdx.x*64;
  const int C = CT*128;

  int arow = rbase + w*16 + cl; if (arow >= n) arow = n-1;
  const bf16x8* Xr = reinterpret_cast<const bf16x8*>(X + (size_t)arow*128);
  bf16x8 a0 = Xr[0+khi], a1 = Xr[4+khi], a2 = Xr[8+khi], a3 = Xr[12+khi];

  for (int ct=0; ct<CT; ++ct){
    __syncthreads();
    {
      int col = t >> 1, k0 = (t & 1)*64;
      const bf16x8* src = reinterpret_cast<const bf16x8*>(Wt + ((size_t)(ct*128+col))*128 + k0);
      bf16x8* dst = reinterpret_cast<bf16x8*>(wl + col*136 + k0);
      #pragma unroll
      for (int i=0;i<8;++i) dst[i] = src[i];
    }
    __syncthreads();

    f32x4 acc[8];
    #pragma unroll
    for (int cf=0;cf<8;++cf) acc[cf] = f32x4{0.f,0.f,0.f,0.f};

    #pragma unroll
    for (int ks=0; ks<4; ++ks){
      bf16x8 av = (ks==0)?a0:(ks==1)?a1:(ks==2)?a2:a3;
      #pragma unroll
      for (int cf=0; cf<8; ++cf){
        bf16x8 bv = *reinterpret_cast<const bf16x8*>(wl + (cf*16+cl)*136 + ks*32 + khi*8);
        acc[cf] = __builtin_amdgcn_mfma_f32_16x16x32_bf16(av, bv, acc[cf], 0, 0, 0);
      }
    }

    #pragma unroll
    for (int j=0;j<4;++j){
      int node = rbase + w*16 + khi*4 + j;
      if (node < n){
        if (OUTFP8){
          unsigned char* Y8 = (unsigned char*)Yv;
          float f0 = acc[0][j]*16.f, f1 = acc[1][j]*16.f, f2 = acc[2][j]*16.f, f3 = acc[3][j]*16.f;
          float f4 = acc[4][j]*16.f, f5 = acc[5][j]*16.f, f6 = acc[6][j]*16.f, f7 = acc[7][j]*16.f;
          int d0 = __builtin_amdgcn_cvt_pk_fp8_f32(f0, f1, 0, false);
          d0     = __builtin_amdgcn_cvt_pk_fp8_f32(f2, f3, d0, true);
          int d1 = __builtin_amdgcn_cvt_pk_fp8_f32(f4, f5, 0, false);
          d1     = __builtin_amdgcn_cvt_pk_fp8_f32(f6, f7, d1, true);
          *reinterpret_cast<uint2*>(Y8 + (size_t)node*128 + cl*8) = make_uint2((uint)d0, (uint)d1);
        } else {
          ushort* Y = (ushort*)Yv;
          ushort* yr = Y + (size_t)node*C + ct*128 + cl;
          #pragma unroll
          for (int cf=0;cf<8;++cf){
            float v = acc[cf][j] + bias[ct*128 + cf*16 + cl];
            yr[cf*16] = bf16bits(v);
          }
        }
      }
    }
  }
}

// ---------------- attention scalars from fp8 permuted hw ----------------
__global__ __launch_bounds__(256) void k_att(const unsigned char* __restrict__ hw8,
        const float* __restrict__ attS, const float* __restrict__ attD,
        float* __restrict__ a_s, float* __restrict__ a_d, int n){
  int wv = threadIdx.x>>6, l = threadIdx.x&63;
  int node = blockIdx.x*4 + wv; if (node>=n) return;
  int hh = l & 3;
  int c0 = 32*hh + (l>>2), c1 = c0 + 16;
  uint us = reinterpret_cast<const ushort*>(hw8 + (size_t)node*128)[l];
  float2 f = fp8x2_to_f2(us);
  float ps = f.x*attS[c0] + f.y*attS[c1];
  float pd = f.x*attD[c0] + f.y*attD[c1];
  #pragma unroll
  for (int m=4;m<64;m<<=1){ ps += __shfl_xor(ps,m); pd += __shfl_xor(pd,m); }
  if (l < 4){
    a_s[(size_t)node*4 + hh] = ps * (1.f/16.f);
    a_d[(size_t)node*4 + hh] = pd * (1.f/16.f);
  }
}

// ---------------- GAT aggregate: fp8 gathers, 4-edge unroll ----------------
__global__ __launch_bounds__(256) void k_gat_agg(const int* __restrict__ rowstart, const int* __restrict__ csr,
              const unsigned char* __restrict__ hw8, const float* __restrict__ a_src,
              const float* __restrict__ a_dst, const float* __restrict__ bias,
              float* __restrict__ h, ushort* __restrict__ hb, int n){
  int wv = threadIdx.x >> 6, l = threadIdx.x & 63;
  int node = blockIdx.x*4 + wv;
  if (node >= n) return;
  int hh = l & 3;
  int c0 = 32*hh + (l>>2), c1 = c0 + 16;
  int start = rowstart[node], end = rowstart[node+1];
  float ad = a_dst[(size_t)node*4 + hh];
  float s = 0.f, ax = 0.f, ay = 0.f;
  const ushort* rows = reinterpret_cast<const ushort*>(hw8);
  int p = start;
  for (; p+3 < end; p += 4){
    int e0 = csr[p]   & 0x7fffffff;
    int e1 = csr[p+1] & 0x7fffffff;
    int e2 = csr[p+2] & 0x7fffffff;
    int e3 = csr[p+3] & 0x7fffffff;
    uint u0 = rows[(size_t)e0*64 + l];
    uint u1 = rows[(size_t)e1*64 + l];
    uint u2 = rows[(size_t)e2*64 + l];
    uint u3 = rows[(size_t)e3*64 + l];
    float s0 = a_src[(size_t)e0*4 + hh] + ad;
    float s1 = a_src[(size_t)e1*4 + hh] + ad;
    float s2 = a_src[(size_t)e2*4 + hh] + ad;
    float s3 = a_src[(size_t)e3*4 + hh] + ad;
    s0 = s0>=0.f?s0:0.2f*s0; s1 = s1>=0.f?s1:0.2f*s1;
    s2 = s2>=0.f?s2:0.2f*s2; s3 = s3>=0.f?s3:0.2f*s3;
    float w0 = __expf(fminf(s0,30.f));
    float w1 = __expf(fminf(s1,30.f));
    float w2 = __expf(fminf(s2,30.f));
    float w3 = __expf(fminf(s3,30.f));
    float2 f0 = fp8x2_to_f2(u0), f1 = fp8x2_to_f2(u1);
    float2 f2 = fp8x2_to_f2(u2), f3 = fp8x2_to_f2(u3);
    s  += (w0+w1)+(w2+w3);
    ax += w0*f0.x + w1*f1.x + w2*f2.x + w3*f3.x;
    ay += w0*f0.y + w1*f1.y + w2*f2.y + w3*f3.y;
  }
  for (; p < end; ++p){
    int e0 = csr[p] & 0x7fffffff;
    float s0 = a_src[(size_t)e0*4 + hh] + ad; s0 = s0>=0.f?s0:0.2f*s0;
    float w0 = __expf(fminf(s0,30.f));
    float2 f0 = fp8x2_to_f2(rows[(size_t)e0*64 + l]);
    s += w0; ax += w0*f0.x; ay += w0*f0.y;
  }
  float inv = 1.f/(s + 1e-16f);
  float ox = ax*inv*(1.f/16.f) + bias[c0];
  float oy = ay*inv*(1.f/16.f) + bias[c1];
  ox = ox > 0.f ? ox : (__expf(ox)-1.f);
  oy = oy > 0.f ? oy : (__expf(oy)-1.f);
  float hx = h[(size_t)node*128 + c0] + ox;
  float hy = h[(size_t)node*128 + c1] + oy;
  h[(size_t)node*128 + c0] = hx;
  h[(size_t)node*128 + c1] = hy;
  hb[(size_t)node*128 + c0] = bf16bits(hx);
  hb[(size_t)node*128 + c1] = bf16bits(hy);
}

// ---------------- transformer aggregate: 4-edge mixed-butterfly ----------------
__global__ __launch_bounds__(256) void k_trans_agg(const int* __restrict__ rowstart, const int* __restrict__ csr,
              const ushort* __restrict__ yb, float* __restrict__ h, int n){
  int wv = threadIdx.x>>6, lane = threadIdx.x&63;
  int node = blockIdx.x*4 + wv;
  if (node >= n) return;
  int li = lane & 15;
  bool odd1 = li & 1, odd2 = li & 2;
  const uint*  y32 = reinterpret_cast<const uint*>(yb);
  const uint2* kvp = reinterpret_cast<const uint2*>(yb);
  float2 q2 = bf2_to_f2(y32[(size_t)node*256 + lane]);   // q pre-scaled by 1/sqrt(32)
  int start = rowstart[node], end = rowstart[node+1];
  float s = 0.f, s_tail = 0.f, ax = 0.f, ay = 0.f;
  int p = start;
  for (; p+3 < end; p += 4){
    int sv0 = csr[p], sv1 = csr[p+1], sv2 = csr[p+2], sv3 = csr[p+3];
    int i0 = sv0 & 0x7fffffff, i1 = sv1 & 0x7fffffff;
    int i2 = sv2 & 0x7fffffff, i3 = sv3 & 0x7fffffff;
    uint2 kv0 = kvp[(size_t)i0*128 + 32 + lane];
    uint2 kv1 = kvp[(size_t)i1*128 + 32 + lane];
    uint2 kv2 = kvp[(size_t)i2*128 + 32 + lane];
    uint2 kv3 = kvp[(size_t)i3*128 + 32 + lane];
    float2 k0 = bf2_to_f2(kv0.x), k1 = bf2_to_f2(kv1.x);
    float2 k2 = bf2_to_f2(kv2.x), k3 = bf2_to_f2(kv3.x);
    float p0 = q2.x*k0.x + q2.y*k0.y;
    float p1 = q2.x*k1.x + q2.y*k1.y;
    float p2 = q2.x*k2.x + q2.y*k2.y;
    float p3 = q2.x*k3.x + q2.y*k3.y;
    // stage 1 (xor1): even lanes keep p0/p2 pair-sums, odd keep p1/p3
    float a = (odd1 ? p1 : p0) + __shfl_xor(odd1 ? p0 : p1, 1);
    float b = (odd1 ? p3 : p2) + __shfl_xor(odd1 ? p2 : p3, 1);
    // stage 2 (xor2): lane li now owns edge (li&3)
    float c = (odd2 ? b : a) + __shfl_xor(odd2 ? a : b, 2);
    c += __shfl_xor(c, 4);
    c += __shfl_xor(c, 8);
    // validity mask (wave-uniform) for self-loop zeroing
    int vb = (sv0>=0?1:0)|(sv1>=0?2:0)|(sv2>=0?4:0)|(sv3>=0?8:0);
    float w = ((vb >> (li&3)) & 1) ? __expf(fminf(c, 30.f)) : 0.f;
    s += w;
    // allgather the 4 weights
    float g1 = __shfl_xor(w, 1);
    float g2 = __shfl_xor(w, 2);
    float g3 = __shfl_xor(g1, 2);
    float A = odd2 ? g3 : g1;
    float B = odd2 ? g2 : w;
    float C = odd2 ? g1 : g3;
    float D = odd2 ? w  : g2;
    float w0 = odd1 ? A : B;
    float w1 = odd1 ? B : A;
    float w2 = odd1 ? C : D;
    float w3 = odd1 ? D : C;
    float2 v0 = bf2_to_f2(kv0.y), v1 = bf2_to_f2(kv1.y);
    float2 v2 = bf2_to_f2(kv2.y), v3 = bf2_to_f2(kv3.y);
    ax += w0*v0.x + w1*v1.x + w2*v2.x + w3*v3.x;
    ay += w0*v0.y + w1*v1.y + w2*v2.y + w3*v3.y;
  }
  for (; p < end; ++p){
    int sv = csr[p];
    int idx = sv & 0x7fffffff;
    uint2 kv = kvp[(size_t)idx*128 + 32 + lane];
    float2 k2 = bf2_to_f2(kv.x);
    float pr = q2.x*k2.x + q2.y*k2.y;
    pr += __shfl_xor(pr,1); pr += __shfl_xor(pr,2);
    pr += __shfl_xor(pr,4); pr += __shfl_xor(pr,8);
    float wt = (sv >= 0) ? __expf(fminf(pr, 30.f)) : 0.f;
    float2 v2 = bf2_to_f2(kv.y);
    s_tail += wt; ax += wt*v2.x; ay += wt*v2.y;
  }
  s += __shfl_xor(s, 1);
  s += __shfl_xor(s, 2);
  s += s_tail;
  float inv = 1.f/(s + 1e-16f);
  float2 sk = bf2_to_f2(y32[(size_t)node*256 + 192 + lane]);
  float tx = ax*inv + sk.x;
  float ty = ay*inv + sk.y;
  tx = tx>0.f?tx:(__expf(tx)-1.f);
  ty = ty>0.f?ty:(__expf(ty)-1.f);
  int d = lane*2;
  float2 hp = *reinterpret_cast<const float2*>(h + (size_t)node*128 + d);
  hp.x += tx; hp.y += ty;
  *reinterpret_cast<float2*>(h + (size_t)node*128 + d) = hp;
}

// ---------------- layernorm (in place) ----------------
__global__ __launch_bounds__(256) void k_ln(float* __restrict__ h, const float* __restrict__ g,
                                            const float* __restrict__ b, int n){
  int wv=threadIdx.x>>6, lane=threadIdx.x&63;
  int node = blockIdx.x*4+wv;
  if(node>=n) return;
  int d=lane*2;
  float2 x = *reinterpret_cast<const float2*>(h+(size_t)node*128+d);
  float sm = x.x + x.y;
  #pragma unroll
  for (int m=1;m<64;m<<=1) sm += __shfl_xor(sm,m);
  float mu = sm * (1.f/128.f);
  float dx = x.x-mu, dy = x.y-mu;
  float vs = dx*dx + dy*dy;
  #pragma unroll
  for (int m=1;m<64;m<<=1) vs += __shfl_xor(vs,m);
  float r = rsqrtf(vs*(1.f/128.f) + 1e-5f);
  float2 gg = *reinterpret_cast<const float2*>(g+d);
  float2 bb = *reinterpret_cast<const float2*>(b+d);
  x.x = dx*r*gg.x + bb.x;
  x.y = dy*r*gg.y + bb.y;
  *reinterpret_cast<float2*>(h+(size_t)node*128+d) = x;
}

// ---------------- pooling ----------------
__global__ void k_gbounds(const int* __restrict__ batch, int* __restrict__ gb, int n, int G){
  int g = blockIdx.x*blockDim.x + threadIdx.x;
  if (g > G) return;
  int lo=0, hi=n;
  while (lo<hi){ int mid=(lo+hi)>>1; if (batch[mid] < g) lo=mid+1; else hi=mid; }
  gb[g] = lo;
}

__global__ void k_pool(const float* __restrict__ hln, const int* __restrict__ gb,
                       float* __restrict__ out, int G){
  int g = blockIdx.x, d = threadIdx.x;   // 128 threads
  int s = gb[g], e = gb[g+1];
  float acc = 0.f;
  for (int i=s;i<e;++i) acc += hln[(size_t)i*128 + d];
  out[(size_t)g*128 + d] = acc / fmaxf((float)(e-s), 1.f);
}

// ---------------- launch ----------------
extern "C" void kernel_launch(void* const* d_in, const int* in_sizes, int n_in,
                              void* d_out, int out_size, void* d_ws, size_t ws_size,
                              hipStream_t stream){
  const int* xn    = (const int*)d_in[0];
  const int* ei    = (const int*)d_in[1];
  const int* batch = (const int*)d_in[2];
  const float* emb  = (const float*)d_in[4];
  const float* demb = (const float*)d_in[5];
  const float* projW= (const float*)d_in[6];
  const float* projB= (const float*)d_in[7];
  const float* gatW = (const float*)d_in[8];
  const float* attS = (const float*)d_in[9];
  const float* attD = (const float*)d_in[10];
  const float* gatB = (const float*)d_in[11];
  const float* Wq = (const float*)d_in[12];
  const float* bq = (const float*)d_in[13];
  const float* Wk = (const float*)d_in[14];
  const float* bk = (const float*)d_in[15];
  const float* Wv = (const float*)d_in[16];
  const float* bv = (const float*)d_in[17];
  const float* Wsk= (const float*)d_in[18];
  const float* bsk= (const float*)d_in[19];
  const float* lng= (const float*)d_in[20];
  const float* lnb= (const float*)d_in[21];
  float* out = (float*)d_out;

  int N = in_sizes[0]/2;
  int E = in_sizes[1]/2;
  int G = out_size/128;
  int T = E + N;

  char* w = (char*)d_ws;
  size_t off = 0;
  auto alloc = [&](size_t bytes)->char*{ char* p = w+off; off += (bytes + 255) & ~(size_t)255; return p; };
  float*  h    = (float*) alloc((size_t)N*128*4);
  ushort* hb   = (ushort*)alloc((size_t)N*128*2);
  ushort* ybuf = (ushort*)alloc((size_t)N*512*2);   // fp8 hw aliases the front during GAT phase
  unsigned char* hw8 = (unsigned char*)ybuf;
  float* a_s  = (float*)alloc((size_t)N*4*4);
  float* a_d  = (float*)alloc((size_t)N*4*4);
  int* deg    = (int*)alloc((size_t)N*4);
  int* cursor = (int*)alloc((size_t)N*4);
  int* rowstart=(int*)alloc((size_t)(N+1)*4);
  int* csr    = (int*)alloc((size_t)T*4);
  int* bsum   = (int*)alloc(4096);
  int* gb     = (int*)alloc((size_t)(G+1)*4);
  float* table= (float*)alloc(180*128*4);
  ushort* wt_gat  = (ushort*)alloc((size_t)3*128*128*2);
  ushort* wt_qkvs = (ushort*)alloc((size_t)512*128*2);
  float* bias512  = (float*)alloc(512*4);
  (void)ws_size; (void)n_in;

  int nb = (N+255)/256;

  k_zero2<<<(N+255)/256,256,0,stream>>>(deg, cursor, N);
  k_table<<<180,128,0,stream>>>(emb, demb, projW, projB, table);
  k_init_h<<<(N*64+255)/256,256,0,stream>>>(xn, table, h, hb, N);
  k_count<<<(T+255)/256,256,0,stream>>>(ei, deg, E, N);
  k_scan_block<<<nb,256,0,stream>>>(deg, rowstart, bsum, N);
  k_scan_sums<<<1,256,0,stream>>>(bsum, nb);
  k_scan_add<<<nb,256,0,stream>>>(rowstart, bsum, N, T);
  k_scatter<<<(T+255)/256,256,0,stream>>>(ei, rowstart, cursor, csr, E, N);
  k_prep_wt_gat<<<192,256,0,stream>>>(gatW, wt_gat);
  k_prep_wt_qkvs<<<256,256,0,stream>>>(Wq, Wk, Wv, Wsk, bq, bk, bv, bsk, wt_qkvs, bias512);

  int gemm_grid = (N+63)/64;
  for (int l=0;l<3;++l){
    k_gemm_mfma<1,1><<<gemm_grid,256,0,stream>>>(hb, wt_gat + (size_t)l*16384, nullptr, hw8, N);
    k_att<<<(N+3)/4,256,0,stream>>>(hw8, attS + l*128, attD + l*128, a_s, a_d, N);
    k_gat_agg<<<(N+3)/4,256,0,stream>>>(rowstart, csr, hw8, a_s, a_d, gatB + l*128, h, hb, N);
  }

  k_gemm_mfma<4,0><<<gemm_grid,256,0,stream>>>(hb, wt_qkvs, bias512, ybuf, N);
  k_trans_agg<<<(N+3)/4,256,0,stream>>>(rowstart, csr, ybuf, h, N);

  k_ln<<<(N+3)/4,256,0,stream>>>(h, lng, lnb, N);
  k_gbounds<<<(G+256)/256,256,0,stream>>>(batch, gb, N, G);
  k_pool<<<G,128,0,stream>>>(h, gb, out, G);
}

// Round 4
// 598.631 us; speedup vs baseline: 2.7616x; 1.1612x over previous
//
#include <hip/hip_runtime.h>
#include <hip/hip_bf16.h>

typedef unsigned int uint;
typedef unsigned short ushort;
typedef __attribute__((ext_vector_type(8))) short bf16x8;
typedef __attribute__((ext_vector_type(4))) float f32x4;
typedef __attribute__((ext_vector_type(2))) float f32x2;

__device__ __forceinline__ float2 bf2_to_f2(uint u){
  union {unsigned int i; float f;} a,b;
  a.i = (u & 0xffffu) << 16;
  b.i = u & 0xffff0000u;
  return make_float2(a.f, b.f);
}
__device__ __forceinline__ ushort bf16bits(float f){
  union{ __hip_bfloat16 h; ushort u;} x; x.h = __float2bfloat16(f); return x.u;
}
__device__ __forceinline__ uint pack_bf2(float x, float y){
  return ((uint)bf16bits(y)<<16) | (uint)bf16bits(x);
}

// ---------------- init / CSR build ----------------

__global__ void k_zero2(int* a, int* b, int n){
  int i = blockIdx.x*blockDim.x + threadIdx.x;
  if (i < n){ a[i]=0; b[i]=0; }
}

__global__ void k_table(const float* __restrict__ emb, const float* __restrict__ demb,
                        const float* __restrict__ W, const float* __restrict__ bias,
                        float* __restrict__ table){
  int d = threadIdx.x;          // 128
  int combo = blockIdx.x;       // 180
  int a = combo/20, b = combo - a*20;
  float acc = bias[d];
  #pragma unroll 8
  for (int i=0;i<32;++i) acc += emb[a*32+i]*W[i*128+d];
  #pragma unroll 8
  for (int i=0;i<32;++i) acc += demb[b*32+i]*W[(32+i)*128+d];
  table[combo*128+d] = acc;
}

__global__ void k_init_h(const int* __restrict__ xn, const float* __restrict__ table,
                         float* __restrict__ h, ushort* __restrict__ hb, int n){
  int gid = blockIdx.x*blockDim.x + threadIdx.x;
  if (gid >= n*64) return;
  int node = gid >> 6, lp = gid & 63;
  int x0 = xn[2*node];
  int x1 = xn[2*node+1]; x1 = x1<0?0:(x1>19?19:x1);
  const float* tr = table + (size_t)(x0*20+x1)*128 + lp*2;
  float a = tr[0], b = tr[1];
  *reinterpret_cast<float2*>(h + (size_t)node*128 + lp*2) = make_float2(a,b);
  reinterpret_cast<uint*>(hb)[(size_t)node*64 + lp] = pack_bf2(a,b);
}

__global__ void k_count(const int* __restrict__ ei, int* __restrict__ deg, int E, int N){
  int e = blockIdx.x*blockDim.x + threadIdx.x;
  if (e >= E+N) return;
  int dst = (e < E) ? ei[E+e] : (e-E);
  atomicAdd(&deg[dst], 1);
}

__global__ __launch_bounds__(256) void k_scan_block(const int* __restrict__ deg, int* __restrict__ rowstart,
                                                    int* __restrict__ bsum, int n){
  int tid = threadIdx.x;
  int gid = blockIdx.x*256 + tid;
  int lane = tid & 63, wv = tid >> 6;
  int v = (gid < n) ? deg[gid] : 0;
  int x = v;
  #pragma unroll
  for (int off=1; off<64; off<<=1){
    int t = __shfl_up(x, off);
    if (lane >= off) x += t;
  }
  __shared__ int wsum[4], woff[4];
  if (lane==63) wsum[wv] = x;
  __syncthreads();
  if (tid==0){
    int r = 0;
    for (int i=0;i<4;++i){ woff[i]=r; r += wsum[i]; }
    bsum[blockIdx.x] = r;
  }
  __syncthreads();
  if (gid < n) rowstart[gid] = x + woff[wv] - v;
}

__global__ __launch_bounds__(256) void k_scan_sums(int* __restrict__ bsum, int nb){
  int tid = threadIdx.x;
  int lane = tid&63, wv = tid>>6;
  int v = (tid<nb)?bsum[tid]:0;
  int x = v;
  #pragma unroll
  for (int off=1;off<64;off<<=1){ int t=__shfl_up(x,off); if(lane>=off) x+=t; }
  __shared__ int wsum[4], woff[4];
  if (lane==63) wsum[wv]=x;
  __syncthreads();
  if (tid==0){ int r=0; for(int i=0;i<4;++i){woff[i]=r;r+=wsum[i];} }
  __syncthreads();
  if (tid<nb) bsum[tid] = x + woff[wv] - v;
}

__global__ void k_scan_add(int* __restrict__ rowstart, const int* __restrict__ bsum, int n, int total){
  int gid = blockIdx.x*256 + threadIdx.x;
  if (gid < n) rowstart[gid] += bsum[blockIdx.x];
  if (gid == 0) rowstart[n] = total;
}

__global__ void k_scatter(const int* __restrict__ ei, const int* __restrict__ rowstart,
                          int* __restrict__ cursor, int* __restrict__ csr, int E, int N){
  int e = blockIdx.x*blockDim.x + threadIdx.x;
  if (e >= E+N) return;
  int dst, sv;
  if (e < E){ dst = ei[E+e]; sv = ei[e]; }
  else { dst = e-E; sv = (e-E) | (int)0x80000000; }   // flag self-loop entries
  int pos = rowstart[dst] + atomicAdd(&cursor[dst], 1);
  csr[pos] = sv;
}

// ---------------- weight prep ----------------

__global__ void k_prep_wt_gat(const float* __restrict__ gatW, ushort* __restrict__ wt){
  int i = blockIdx.x*256 + threadIdx.x;   // < 3*128*128
  int l = i >> 14, rem = i & 16383, c = rem >> 7, k = rem & 127;
  wt[i] = bf16bits(gatW[l*16384 + k*128 + c]);
}

// fused q | kv(fp8-quad permuted) | skip. GEMM col c -> canonical source col:
//  c in [0,128):   q col c, scaled 1/(sqrt(32)*16)  (absorbs k's x16 fp8 scale)
//  c in [128,384): ct=c>>7, cf=(c&127)>>4, cl=c&15; m=cl+16*((ct-1)*2+(cf>>2)); wn=cf&3
//                  wn<2 -> k col 2m+wn ; else v col 2m+wn-2
//  c in [384,512): skip col c-384
__global__ void k_prep_wt_qkvs(const float* __restrict__ Wq, const float* __restrict__ Wk,
                               const float* __restrict__ Wv, const float* __restrict__ Ws,
                               const float* __restrict__ bq, const float* __restrict__ bk,
                               const float* __restrict__ bv, const float* __restrict__ bs,
                               ushort* __restrict__ wt, float* __restrict__ bias){
  int i = blockIdx.x*256 + threadIdx.x;   // < 512*128
  int c = i >> 7, k = i & 127;
  const float* W; const float* B; int sc; float scale = 1.f;
  if (c < 128){ W = Wq; B = bq; sc = c; scale = 0.011048543456039805f; } // 1/(sqrt(32)*16)
  else if (c < 384){
    int ct = c >> 7, within = c & 127, cf = within >> 4, cl = within & 15;
    int m = cl + 16*((ct-1)*2 + (cf>>2));
    int wn = cf & 3;
    if (wn < 2){ W = Wk; B = bk; sc = 2*m + wn; }
    else       { W = Wv; B = bv; sc = 2*m + wn - 2; }
  } else { W = Ws; B = bs; sc = c - 384; }
  wt[c*128 + k] = bf16bits(W[k*128 + sc] * scale);
  if (k == 0) bias[c] = B[sc] * scale;
}

// ---------------- MFMA GEMM ----------------
// MODE 1: CT=1, GAT: Y fp8 (x16), permuted: byte pos cl*8+cf holds col cf*16+cl.
// MODE 2: CT=4, fused: ct0 -> q bf16 (Yq), ct1/2 -> kv fp8 quads (Ykv), ct3 -> skip bf16 (Ysk).
template<int CT, int MODE>
__global__ __launch_bounds__(256) void k_gemm_mfma(const ushort* __restrict__ X,
        const ushort* __restrict__ Wt, const float* __restrict__ bias,
        void* __restrict__ Yq, uint* __restrict__ Ykv, ushort* __restrict__ Ysk, int n){
  __shared__ ushort wl[128*136];
  const int t = threadIdx.x;
  const int w = t >> 6, lane = t & 63;
  const int cl = lane & 15, khi = lane >> 4;
  const int rbase = blockIdx.x*64;

  int arow = rbase + w*16 + cl; if (arow >= n) arow = n-1;
  const bf16x8* Xr = reinterpret_cast<const bf16x8*>(X + (size_t)arow*128);
  bf16x8 a0 = Xr[0+khi], a1 = Xr[4+khi], a2 = Xr[8+khi], a3 = Xr[12+khi];

  for (int ct=0; ct<CT; ++ct){
    __syncthreads();
    {
      int col = t >> 1, k0 = (t & 1)*64;
      const bf16x8* src = reinterpret_cast<const bf16x8*>(Wt + ((size_t)(ct*128+col))*128 + k0);
      bf16x8* dst = reinterpret_cast<bf16x8*>(wl + col*136 + k0);
      #pragma unroll
      for (int i=0;i<8;++i) dst[i] = src[i];
    }
    __syncthreads();

    f32x4 acc[8];
    #pragma unroll
    for (int cf=0;cf<8;++cf) acc[cf] = f32x4{0.f,0.f,0.f,0.f};

    #pragma unroll
    for (int ks=0; ks<4; ++ks){
      bf16x8 av = (ks==0)?a0:(ks==1)?a1:(ks==2)?a2:a3;
      #pragma unroll
      for (int cf=0; cf<8; ++cf){
        bf16x8 bv = *reinterpret_cast<const bf16x8*>(wl + (cf*16+cl)*136 + ks*32 + khi*8);
        acc[cf] = __builtin_amdgcn_mfma_f32_16x16x32_bf16(av, bv, acc[cf], 0, 0, 0);
      }
    }

    #pragma unroll
    for (int j=0;j<4;++j){
      int node = rbase + w*16 + khi*4 + j;
      if (node < n){
        if (MODE==1){
          unsigned char* Y8 = (unsigned char*)Yq;
          float f0 = acc[0][j]*16.f, f1 = acc[1][j]*16.f, f2 = acc[2][j]*16.f, f3 = acc[3][j]*16.f;
          float f4 = acc[4][j]*16.f, f5 = acc[5][j]*16.f, f6 = acc[6][j]*16.f, f7 = acc[7][j]*16.f;
          int d0 = __builtin_amdgcn_cvt_pk_fp8_f32(f0, f1, 0, false);
          d0     = __builtin_amdgcn_cvt_pk_fp8_f32(f2, f3, d0, true);
          int d1 = __builtin_amdgcn_cvt_pk_fp8_f32(f4, f5, 0, false);
          d1     = __builtin_amdgcn_cvt_pk_fp8_f32(f6, f7, d1, true);
          *reinterpret_cast<uint2*>(Y8 + (size_t)node*128 + cl*8) = make_uint2((uint)d0, (uint)d1);
        } else {
          if (ct == 0 || ct == 3){
            ushort* Y = (ct == 0) ? (ushort*)Yq : Ysk;
            ushort* yr = Y + (size_t)node*128 + cl;
            #pragma unroll
            for (int cf=0;cf<8;++cf)
              yr[cf*16] = bf16bits(acc[cf][j] + bias[ct*128 + cf*16 + cl]);
          } else {
            #pragma unroll
            for (int g=0; g<2; ++g){
              float f0 = (acc[g*4+0][j] + bias[ct*128 + (g*4+0)*16 + cl])*16.f;
              float f1 = (acc[g*4+1][j] + bias[ct*128 + (g*4+1)*16 + cl])*16.f;
              float f2 = (acc[g*4+2][j] + bias[ct*128 + (g*4+2)*16 + cl])*16.f;
              float f3 = (acc[g*4+3][j] + bias[ct*128 + (g*4+3)*16 + cl])*16.f;
              int d = __builtin_amdgcn_cvt_pk_fp8_f32(f0, f1, 0, false);
              d     = __builtin_amdgcn_cvt_pk_fp8_f32(f2, f3, d, true);
              int m = cl + 16*((ct-1)*2 + g);
              Ykv[(size_t)node*64 + m] = (uint)d;
            }
          }
        }
      }
    }
  }
}

// ---------------- attention scalars from fp8 permuted hw ----------------
__global__ __launch_bounds__(256) void k_att(const unsigned char* __restrict__ hw8,
        const float* __restrict__ attS, const float* __restrict__ attD,
        float* __restrict__ a_s, float* __restrict__ a_d, int n){
  int wv = threadIdx.x>>6, l = threadIdx.x&63;
  int node = blockIdx.x*4 + wv; if (node>=n) return;
  int hh = l & 3;
  int c0 = 32*hh + (l>>2), c1 = c0 + 16;
  uint us = reinterpret_cast<const ushort*>(hw8 + (size_t)node*128)[l];
  f32x2 f = __builtin_amdgcn_cvt_pk_f32_fp8((int)us, false);
  float ps = f.x*attS[c0] + f.y*attS[c1];
  float pd = f.x*attD[c0] + f.y*attD[c1];
  #pragma unroll
  for (int m=4;m<64;m<<=1){ ps += __shfl_xor(ps,m); pd += __shfl_xor(pd,m); }
  if (l < 4){
    a_s[(size_t)node*4 + hh] = ps * (1.f/16.f);
    a_d[(size_t)node*4 + hh] = pd * (1.f/16.f);
  }
}

// ---------------- GAT aggregate: fp8 gathers, 4-edge unroll ----------------
__global__ __launch_bounds__(256) void k_gat_agg(const int* __restrict__ rowstart, const int* __restrict__ csr,
              const unsigned char* __restrict__ hw8, const float* __restrict__ a_src,
              const float* __restrict__ a_dst, const float* __restrict__ bias,
              float* __restrict__ h, ushort* __restrict__ hb, int n){
  int wv = threadIdx.x >> 6, l = threadIdx.x & 63;
  int node = blockIdx.x*4 + wv;
  if (node >= n) return;
  int hh = l & 3;
  int c0 = 32*hh + (l>>2), c1 = c0 + 16;
  int start = rowstart[node], end = rowstart[node+1];
  float ad = a_dst[(size_t)node*4 + hh];
  float s = 0.f, ax = 0.f, ay = 0.f;
  const ushort* rows = reinterpret_cast<const ushort*>(hw8);
  int p = start;
  for (; p+3 < end; p += 4){
    int e0 = csr[p]   & 0x7fffffff;
    int e1 = csr[p+1] & 0x7fffffff;
    int e2 = csr[p+2] & 0x7fffffff;
    int e3 = csr[p+3] & 0x7fffffff;
    uint u0 = rows[(size_t)e0*64 + l];
    uint u1 = rows[(size_t)e1*64 + l];
    uint u2 = rows[(size_t)e2*64 + l];
    uint u3 = rows[(size_t)e3*64 + l];
    float s0 = a_src[(size_t)e0*4 + hh] + ad;
    float s1 = a_src[(size_t)e1*4 + hh] + ad;
    float s2 = a_src[(size_t)e2*4 + hh] + ad;
    float s3 = a_src[(size_t)e3*4 + hh] + ad;
    s0 = s0>=0.f?s0:0.2f*s0; s1 = s1>=0.f?s1:0.2f*s1;
    s2 = s2>=0.f?s2:0.2f*s2; s3 = s3>=0.f?s3:0.2f*s3;
    float w0 = __expf(fminf(s0,30.f));
    float w1 = __expf(fminf(s1,30.f));
    float w2 = __expf(fminf(s2,30.f));
    float w3 = __expf(fminf(s3,30.f));
    f32x2 f0 = __builtin_amdgcn_cvt_pk_f32_fp8((int)u0, false);
    f32x2 f1 = __builtin_amdgcn_cvt_pk_f32_fp8((int)u1, false);
    f32x2 f2 = __builtin_amdgcn_cvt_pk_f32_fp8((int)u2, false);
    f32x2 f3 = __builtin_amdgcn_cvt_pk_f32_fp8((int)u3, false);
    s  += (w0+w1)+(w2+w3);
    ax += w0*f0.x + w1*f1.x + w2*f2.x + w3*f3.x;
    ay += w0*f0.y + w1*f1.y + w2*f2.y + w3*f3.y;
  }
  for (; p < end; ++p){
    int e0 = csr[p] & 0x7fffffff;
    float s0 = a_src[(size_t)e0*4 + hh] + ad; s0 = s0>=0.f?s0:0.2f*s0;
    float w0 = __expf(fminf(s0,30.f));
    f32x2 f0 = __builtin_amdgcn_cvt_pk_f32_fp8((int)(uint)rows[(size_t)e0*64 + l], false);
    s += w0; ax += w0*f0.x; ay += w0*f0.y;
  }
  float inv = 1.f/(s + 1e-16f);
  float ox = ax*inv*(1.f/16.f) + bias[c0];
  float oy = ay*inv*(1.f/16.f) + bias[c1];
  ox = ox > 0.f ? ox : (__expf(ox)-1.f);
  oy = oy > 0.f ? oy : (__expf(oy)-1.f);
  float hx = h[(size_t)node*128 + c0] + ox;
  float hy = h[(size_t)node*128 + c1] + oy;
  h[(size_t)node*128 + c0] = hx;
  h[(size_t)node*128 + c1] = hy;
  hb[(size_t)node*128 + c0] = bf16bits(hx);
  hb[(size_t)node*128 + c1] = bf16bits(hy);
}

// ---------------- transformer aggregate: fp8 kv quads, 4-edge mixed-butterfly ----------------
__global__ __launch_bounds__(256) void k_trans_agg(const int* __restrict__ rowstart, const int* __restrict__ csr,
              const ushort* __restrict__ yq, const uint* __restrict__ ykv,
              const ushort* __restrict__ ysk, float* __restrict__ h, int n){
  int wv = threadIdx.x>>6, lane = threadIdx.x&63;
  int node = blockIdx.x*4 + wv;
  if (node >= n) return;
  int li = lane & 15;
  bool odd1 = li & 1, odd2 = li & 2;
  const uint* q32 = reinterpret_cast<const uint*>(yq);
  const uint* s32 = reinterpret_cast<const uint*>(ysk);
  float2 q2 = bf2_to_f2(q32[(size_t)node*64 + lane]);   // q pre-scaled by 1/(sqrt(32)*16)
  int start = rowstart[node], end = rowstart[node+1];
  float s = 0.f, s_tail = 0.f, ax = 0.f, ay = 0.f;
  int p = start;
  for (; p+3 < end; p += 4){
    int sv0 = csr[p], sv1 = csr[p+1], sv2 = csr[p+2], sv3 = csr[p+3];
    int i0 = sv0 & 0x7fffffff, i1 = sv1 & 0x7fffffff;
    int i2 = sv2 & 0x7fffffff, i3 = sv3 & 0x7fffffff;
    uint u0 = ykv[(size_t)i0*64 + lane];
    uint u1 = ykv[(size_t)i1*64 + lane];
    uint u2 = ykv[(size_t)i2*64 + lane];
    uint u3 = ykv[(size_t)i3*64 + lane];
    f32x2 k0 = __builtin_amdgcn_cvt_pk_f32_fp8((int)u0, false);
    f32x2 k1 = __builtin_amdgcn_cvt_pk_f32_fp8((int)u1, false);
    f32x2 k2 = __builtin_amdgcn_cvt_pk_f32_fp8((int)u2, false);
    f32x2 k3 = __builtin_amdgcn_cvt_pk_f32_fp8((int)u3, false);
    float p0 = q2.x*k0.x + q2.y*k0.y;
    float p1 = q2.x*k1.x + q2.y*k1.y;
    float p2 = q2.x*k2.x + q2.y*k2.y;
    float p3 = q2.x*k3.x + q2.y*k3.y;
    // stage 1 (xor1)
    float a = (odd1 ? p1 : p0) + __shfl_xor(odd1 ? p0 : p1, 1);
    float b = (odd1 ? p3 : p2) + __shfl_xor(odd1 ? p2 : p3, 1);
    // stage 2 (xor2): lane li owns edge (li&3)
    float c = (odd2 ? b : a) + __shfl_xor(odd2 ? a : b, 2);
    c += __shfl_xor(c, 4);
    c += __shfl_xor(c, 8);
    int vb = (sv0>=0?1:0)|(sv1>=0?2:0)|(sv2>=0?4:0)|(sv3>=0?8:0);
    float w = ((vb >> (li&3)) & 1) ? __expf(fminf(c, 30.f)) : 0.f;
    s += w;
    float g1 = __shfl_xor(w, 1);
    float g2 = __shfl_xor(w, 2);
    float g3 = __shfl_xor(g1, 2);
    float A = odd2 ? g3 : g1;
    float B = odd2 ? g2 : w;
    float C = odd2 ? g1 : g3;
    float D = odd2 ? w  : g2;
    float w0 = odd1 ? A : B;
    float w1 = odd1 ? B : A;
    float w2 = odd1 ? C : D;
    float w3 = odd1 ? D : C;
    f32x2 v0 = __builtin_amdgcn_cvt_pk_f32_fp8((int)u0, true);
    f32x2 v1 = __builtin_amdgcn_cvt_pk_f32_fp8((int)u1, true);
    f32x2 v2 = __builtin_amdgcn_cvt_pk_f32_fp8((int)u2, true);
    f32x2 v3 = __builtin_amdgcn_cvt_pk_f32_fp8((int)u3, true);
    ax += w0*v0.x + w1*v1.x + w2*v2.x + w3*v3.x;
    ay += w0*v0.y + w1*v1.y + w2*v2.y + w3*v3.y;
  }
  for (; p < end; ++p){
    int sv = csr[p];
    int idx = sv & 0x7fffffff;
    uint u = ykv[(size_t)idx*64 + lane];
    f32x2 k2 = __builtin_amdgcn_cvt_pk_f32_fp8((int)u, false);
    float pr = q2.x*k2.x + q2.y*k2.y;
    pr += __shfl_xor(pr,1); pr += __shfl_xor(pr,2);
    pr += __shfl_xor(pr,4); pr += __shfl_xor(pr,8);
    float wt = (sv >= 0) ? __expf(fminf(pr, 30.f)) : 0.f;
    f32x2 v2 = __builtin_amdgcn_cvt_pk_f32_fp8((int)u, true);
    s_tail += wt; ax += wt*v2.x; ay += wt*v2.y;
  }
  s += __shfl_xor(s, 1);
  s += __shfl_xor(s, 2);
  s += s_tail;
  float inv = (1.f/16.f)/(s + 1e-16f);       // fold out v's x16 scale
  float2 sk = bf2_to_f2(s32[(size_t)node*64 + lane]);
  float tx = ax*inv + sk.x;
  float ty = ay*inv + sk.y;
  tx = tx>0.f?tx:(__expf(tx)-1.f);
  ty = ty>0.f?ty:(__expf(ty)-1.f);
  int d = lane*2;
  float2 hp = *reinterpret_cast<const float2*>(h + (size_t)node*128 + d);
  hp.x += tx; hp.y += ty;
  *reinterpret_cast<float2*>(h + (size_t)node*128 + d) = hp;
}

// ---------------- layernorm (in place) ----------------
__global__ __launch_bounds__(256) void k_ln(float* __restrict__ h, const float* __restrict__ g,
                                            const float* __restrict__ b, int n){
  int wv=threadIdx.x>>6, lane=threadIdx.x&63;
  int node = blockIdx.x*4+wv;
  if(node>=n) return;
  int d=lane*2;
  float2 x = *reinterpret_cast<const float2*>(h+(size_t)node*128+d);
  float sm = x.x + x.y;
  #pragma unroll
  for (int m=1;m<64;m<<=1) sm += __shfl_xor(sm,m);
  float mu = sm * (1.f/128.f);
  float dx = x.x-mu, dy = x.y-mu;
  float vs = dx*dx + dy*dy;
  #pragma unroll
  for (int m=1;m<64;m<<=1) vs += __shfl_xor(vs,m);
  float r = rsqrtf(vs*(1.f/128.f) + 1e-5f);
  float2 gg = *reinterpret_cast<const float2*>(g+d);
  float2 bb = *reinterpret_cast<const float2*>(b+d);
  x.x = dx*r*gg.x + bb.x;
  x.y = dy*r*gg.y + bb.y;
  *reinterpret_cast<float2*>(h+(size_t)node*128+d) = x;
}

// ---------------- pooling ----------------
__global__ void k_gbounds(const int* __restrict__ batch, int* __restrict__ gb, int n, int G){
  int g = blockIdx.x*blockDim.x + threadIdx.x;
  if (g > G) return;
  int lo=0, hi=n;
  while (lo<hi){ int mid=(lo+hi)>>1; if (batch[mid] < g) lo=mid+1; else hi=mid; }
  gb[g] = lo;
}

__global__ void k_pool(const float* __restrict__ hln, const int* __restrict__ gb,
                       float* __restrict__ out, int G){
  int g = blockIdx.x, d = threadIdx.x;   // 128 threads
  int s = gb[g], e = gb[g+1];
  float acc = 0.f;
  for (int i=s;i<e;++i) acc += hln[(size_t)i*128 + d];
  out[(size_t)g*128 + d] = acc / fmaxf((float)(e-s), 1.f);
}

// ---------------- launch ----------------
extern "C" void kernel_launch(void* const* d_in, const int* in_sizes, int n_in,
                              void* d_out, int out_size, void* d_ws, size_t ws_size,
                              hipStream_t stream){
  const int* xn    = (const int*)d_in[0];
  const int* ei    = (const int*)d_in[1];
  const int* batch = (const int*)d_in[2];
  const float* emb  = (const float*)d_in[4];
  const float* demb = (const float*)d_in[5];
  const float* projW= (const float*)d_in[6];
  const float* projB= (const float*)d_in[7];
  const float* gatW = (const float*)d_in[8];
  const float* attS = (const float*)d_in[9];
  const float* attD = (const float*)d_in[10];
  const float* gatB = (const float*)d_in[11];
  const float* Wq = (const float*)d_in[12];
  const float* bq = (const float*)d_in[13];
  const float* Wk = (const float*)d_in[14];
  const float* bk = (const float*)d_in[15];
  const float* Wv = (const float*)d_in[16];
  const float* bv = (const float*)d_in[17];
  const float* Wsk= (const float*)d_in[18];
  const float* bsk= (const float*)d_in[19];
  const float* lng= (const float*)d_in[20];
  const float* lnb= (const float*)d_in[21];
  float* out = (float*)d_out;

  int N = in_sizes[0]/2;
  int E = in_sizes[1]/2;
  int G = out_size/128;
  int T = E + N;

  char* w = (char*)d_ws;
  size_t off = 0;
  auto alloc = [&](size_t bytes)->char*{ char* p = w+off; off += (bytes + 255) & ~(size_t)255; return p; };
  float*  h    = (float*) alloc((size_t)N*128*4);
  ushort* hb   = (ushort*)alloc((size_t)N*128*2);
  ushort* yq   = (ushort*)alloc((size_t)N*128*2);   // q bf16; fp8 hw aliases its front half
  uint*   ykv  = (uint*)  alloc((size_t)N*64*4);    // fp8 kv quads
  ushort* ysk  = (ushort*)alloc((size_t)N*128*2);   // skip bf16
  unsigned char* hw8 = (unsigned char*)yq;
  float* a_s  = (float*)alloc((size_t)N*4*4);
  float* a_d  = (float*)alloc((size_t)N*4*4);
  int* deg    = (int*)alloc((size_t)N*4);
  int* cursor = (int*)alloc((size_t)N*4);
  int* rowstart=(int*)alloc((size_t)(N+1)*4);
  int* csr    = (int*)alloc((size_t)T*4);
  int* bsum   = (int*)alloc(4096);
  int* gb     = (int*)alloc((size_t)(G+1)*4);
  float* table= (float*)alloc(180*128*4);
  ushort* wt_gat  = (ushort*)alloc((size_t)3*128*128*2);
  ushort* wt_qkvs = (ushort*)alloc((size_t)512*128*2);
  float* bias512  = (float*)alloc(512*4);
  (void)ws_size; (void)n_in;

  int nb = (N+255)/256;

  k_zero2<<<(N+255)/256,256,0,stream>>>(deg, cursor, N);
  k_table<<<180,128,0,stream>>>(emb, demb, projW, projB, table);
  k_init_h<<<(N*64+255)/256,256,0,stream>>>(xn, table, h, hb, N);
  k_count<<<(T+255)/256,256,0,stream>>>(ei, deg, E, N);
  k_scan_block<<<nb,256,0,stream>>>(deg, rowstart, bsum, N);
  k_scan_sums<<<1,256,0,stream>>>(bsum, nb);
  k_scan_add<<<nb,256,0,stream>>>(rowstart, bsum, N, T);
  k_scatter<<<(T+255)/256,256,0,stream>>>(ei, rowstart, cursor, csr, E, N);
  k_prep_wt_gat<<<192,256,0,stream>>>(gatW, wt_gat);
  k_prep_wt_qkvs<<<256,256,0,stream>>>(Wq, Wk, Wv, Wsk, bq, bk, bv, bsk, wt_qkvs, bias512);

  int gemm_grid = (N+63)/64;
  for (int l=0;l<3;++l){
    k_gemm_mfma<1,1><<<gemm_grid,256,0,stream>>>(hb, wt_gat + (size_t)l*16384, nullptr,
                                                 hw8, nullptr, nullptr, N);
    k_att<<<(N+3)/4,256,0,stream>>>(hw8, attS + l*128, attD + l*128, a_s, a_d, N);
    k_gat_agg<<<(N+3)/4,256,0,stream>>>(rowstart, csr, hw8, a_s, a_d, gatB + l*128, h, hb, N);
  }

  k_gemm_mfma<4,2><<<gemm_grid,256,0,stream>>>(hb, wt_qkvs, bias512, yq, ykv, ysk, N);
  k_trans_agg<<<(N+3)/4,256,0,stream>>>(rowstart, csr, yq, ykv, ysk, h, N);

  k_ln<<<(N+3)/4,256,0,stream>>>(h, lng, lnb, N);
  k_gbounds<<<(G+256)/256,256,0,stream>>>(batch, gb, N, G);
  k_pool<<<G,128,0,stream>>>(h, gb, out, G);
}

// Round 5
// 515.970 us; speedup vs baseline: 3.2040x; 1.1602x over previous
//
#include <hip/hip_runtime.h>
#include <hip/hip_bf16.h>

typedef unsigned int uint;
typedef unsigned short ushort;
typedef __attribute__((ext_vector_type(8))) short bf16x8;
typedef __attribute__((ext_vector_type(4))) float f32x4;
typedef __attribute__((ext_vector_type(2))) float f32x2;

__device__ __forceinline__ float2 bf2_to_f2(uint u){
  union {unsigned int i; float f;} a,b;
  a.i = (u & 0xffffu) << 16;
  b.i = u & 0xffff0000u;
  return make_float2(a.f, b.f);
}
__device__ __forceinline__ ushort bf16bits(float f){
  union{ __hip_bfloat16 h; ushort u;} x; x.h = __float2bfloat16(f); return x.u;
}
__device__ __forceinline__ uint pack_bf2(float x, float y){
  return ((uint)bf16bits(y)<<16) | (uint)bf16bits(x);
}

// ---------------- init / CSR build ----------------

__global__ void k_zero1(int* a, int n){
  int i = blockIdx.x*blockDim.x + threadIdx.x;
  if (i < n) a[i] = 0;
}

// h0 = concat(emb[a], depth_emb[b]) @ projW + projB : only 9*20=180 combos
__global__ void k_table(const float* __restrict__ emb, const float* __restrict__ demb,
                        const float* __restrict__ W, const float* __restrict__ bias,
                        float* __restrict__ table){
  int d = threadIdx.x;          // 128
  int combo = blockIdx.x;       // 180
  int a = combo/20, b = combo - a*20;
  float acc = bias[d];
  #pragma unroll 8
  for (int i=0;i<32;++i) acc += emb[a*32+i]*W[i*128+d];
  #pragma unroll 8
  for (int i=0;i<32;++i) acc += demb[b*32+i]*W[(32+i)*128+d];
  table[combo*128+d] = acc;
}

__global__ void k_init_h(const int* __restrict__ xn, const float* __restrict__ table,
                         float* __restrict__ h, ushort* __restrict__ hb, int n){
  int gid = blockIdx.x*blockDim.x + threadIdx.x;
  if (gid >= n*64) return;
  int node = gid >> 6, lp = gid & 63;
  int x0 = xn[2*node];
  int x1 = xn[2*node+1]; x1 = x1<0?0:(x1>19?19:x1);
  const float* tr = table + (size_t)(x0*20+x1)*128 + lp*2;
  float a = tr[0], b = tr[1];
  *reinterpret_cast<float2*>(h + (size_t)node*128 + lp*2) = make_float2(a,b);
  reinterpret_cast<uint*>(hb)[(size_t)node*64 + lp] = pack_bf2(a,b);
}

// rank[e] = arrival index within dst row; cnt accumulates degree (real edges only)
__global__ void k_rank(const int* __restrict__ ei, int* __restrict__ cnt,
                       int* __restrict__ rank, int E){
  int e = blockIdx.x*blockDim.x + threadIdx.x;
  if (e >= E) return;
  rank[e] = atomicAdd(&cnt[ei[E+e]], 1);
}

__global__ __launch_bounds__(256) void k_scan_block(const int* __restrict__ deg, int* __restrict__ rowstart,
                                                    int* __restrict__ bsum, int n){
  int tid = threadIdx.x;
  int gid = blockIdx.x*256 + tid;
  int lane = tid & 63, wv = tid >> 6;
  int v = (gid < n) ? deg[gid] : 0;
  int x = v;
  #pragma unroll
  for (int off=1; off<64; off<<=1){
    int t = __shfl_up(x, off);
    if (lane >= off) x += t;
  }
  __shared__ int wsum[4], woff[4];
  if (lane==63) wsum[wv] = x;
  __syncthreads();
  if (tid==0){
    int r = 0;
    for (int i=0;i<4;++i){ woff[i]=r; r += wsum[i]; }
    bsum[blockIdx.x] = r;
  }
  __syncthreads();
  if (gid < n) rowstart[gid] = x + woff[wv] - v;
}

__global__ __launch_bounds__(256) void k_scan_sums(int* __restrict__ bsum, int nb){
  int tid = threadIdx.x;
  int lane = tid&63, wv = tid>>6;
  int v = (tid<nb)?bsum[tid]:0;
  int x = v;
  #pragma unroll
  for (int off=1;off<64;off<<=1){ int t=__shfl_up(x,off); if(lane>=off) x+=t; }
  __shared__ int wsum[4], woff[4];
  if (lane==63) wsum[wv]=x;
  __syncthreads();
  if (tid==0){ int r=0; for(int i=0;i<4;++i){woff[i]=r;r+=wsum[i];} }
  __syncthreads();
  if (tid<nb) bsum[tid] = x + woff[wv] - v;
}

__global__ void k_scan_add(int* __restrict__ rowstart, const int* __restrict__ bsum, int n, int total){
  int gid = blockIdx.x*256 + threadIdx.x;
  if (gid < n) rowstart[gid] += bsum[blockIdx.x];
  if (gid == 0) rowstart[n] = total;
}

__global__ void k_place(const int* __restrict__ ei, const int* __restrict__ rowstart,
                        const int* __restrict__ rank, ushort* __restrict__ csr16, int E){
  int e = blockIdx.x*blockDim.x + threadIdx.x;
  if (e >= E) return;
  csr16[rowstart[ei[E+e]] + rank[e]] = (ushort)ei[e];
}

// ---------------- weight prep ----------------

__global__ void k_prep_wt_gat(const float* __restrict__ gatW, ushort* __restrict__ wt){
  int i = blockIdx.x*256 + threadIdx.x;   // < 3*128*128
  int l = i >> 14, rem = i & 16383, c = rem >> 7, k = rem & 127;
  wt[i] = bf16bits(gatW[l*16384 + k*128 + c]);
}

// fused q | kv(fp8-quad permuted) | skip. GEMM col c -> canonical source col:
//  c in [0,128):   q col c, scaled 1/(sqrt(32)*16)  (absorbs k's x16 fp8 scale)
//  c in [128,384): ct=c>>7, cf=(c&127)>>4, cl=c&15; m=cl+16*((ct-1)*2+(cf>>2)); wn=cf&3
//                  wn<2 -> k col 2m+wn ; else v col 2m+wn-2
//  c in [384,512): skip col c-384
__global__ void k_prep_wt_qkvs(const float* __restrict__ Wq, const float* __restrict__ Wk,
                               const float* __restrict__ Wv, const float* __restrict__ Ws,
                               const float* __restrict__ bq, const float* __restrict__ bk,
                               const float* __restrict__ bv, const float* __restrict__ bs,
                               ushort* __restrict__ wt, float* __restrict__ bias){
  int i = blockIdx.x*256 + threadIdx.x;   // < 512*128
  int c = i >> 7, k = i & 127;
  const float* W; const float* B; int sc; float scale = 1.f;
  if (c < 128){ W = Wq; B = bq; sc = c; scale = 0.011048543456039805f; } // 1/(sqrt(32)*16)
  else if (c < 384){
    int ct = c >> 7, within = c & 127, cf = within >> 4, cl = within & 15;
    int m = cl + 16*((ct-1)*2 + (cf>>2));
    int wn = cf & 3;
    if (wn < 2){ W = Wk; B = bk; sc = 2*m + wn; }
    else       { W = Wv; B = bv; sc = 2*m + wn - 2; }
  } else { W = Ws; B = bs; sc = c - 384; }
  wt[c*128 + k] = bf16bits(W[k*128 + sc] * scale);
  if (k == 0) bias[c] = B[sc] * scale;
}

// ---------------- MFMA GEMM ----------------
// MODE 1: CT=1, GAT: Y fp8 (x16), permuted: byte pos cl*8+cf holds col cf*16+cl.
// MODE 2: CT=4, fused: ct0 -> q bf16 (Yq), ct1/2 -> kv fp8 quads (Ykv), ct3 -> skip bf16 (Ysk).
template<int CT, int MODE>
__global__ __launch_bounds__(256) void k_gemm_mfma(const ushort* __restrict__ X,
        const ushort* __restrict__ Wt, const float* __restrict__ bias,
        void* __restrict__ Yq, uint* __restrict__ Ykv, ushort* __restrict__ Ysk, int n){
  __shared__ ushort wl[128*136];
  const int t = threadIdx.x;
  const int w = t >> 6, lane = t & 63;
  const int cl = lane & 15, khi = lane >> 4;
  const int rbase = blockIdx.x*64;

  int arow = rbase + w*16 + cl; if (arow >= n) arow = n-1;
  const bf16x8* Xr = reinterpret_cast<const bf16x8*>(X + (size_t)arow*128);
  bf16x8 a0 = Xr[0+khi], a1 = Xr[4+khi], a2 = Xr[8+khi], a3 = Xr[12+khi];

  for (int ct=0; ct<CT; ++ct){
    __syncthreads();
    {
      int col = t >> 1, k0 = (t & 1)*64;
      const bf16x8* src = reinterpret_cast<const bf16x8*>(Wt + ((size_t)(ct*128+col))*128 + k0);
      bf16x8* dst = reinterpret_cast<bf16x8*>(wl + col*136 + k0);
      #pragma unroll
      for (int i=0;i<8;++i) dst[i] = src[i];
    }
    __syncthreads();

    f32x4 acc[8];
    #pragma unroll
    for (int cf=0;cf<8;++cf) acc[cf] = f32x4{0.f,0.f,0.f,0.f};

    #pragma unroll
    for (int ks=0; ks<4; ++ks){
      bf16x8 av = (ks==0)?a0:(ks==1)?a1:(ks==2)?a2:a3;
      #pragma unroll
      for (int cf=0; cf<8; ++cf){
        bf16x8 bv = *reinterpret_cast<const bf16x8*>(wl + (cf*16+cl)*136 + ks*32 + khi*8);
        acc[cf] = __builtin_amdgcn_mfma_f32_16x16x32_bf16(av, bv, acc[cf], 0, 0, 0);
      }
    }

    #pragma unroll
    for (int j=0;j<4;++j){
      int node = rbase + w*16 + khi*4 + j;
      if (node < n){
        if (MODE==1){
          unsigned char* Y8 = (unsigned char*)Yq;
          float f0 = acc[0][j]*16.f, f1 = acc[1][j]*16.f, f2 = acc[2][j]*16.f, f3 = acc[3][j]*16.f;
          float f4 = acc[4][j]*16.f, f5 = acc[5][j]*16.f, f6 = acc[6][j]*16.f, f7 = acc[7][j]*16.f;
          int d0 = __builtin_amdgcn_cvt_pk_fp8_f32(f0, f1, 0, false);
          d0     = __builtin_amdgcn_cvt_pk_fp8_f32(f2, f3, d0, true);
          int d1 = __builtin_amdgcn_cvt_pk_fp8_f32(f4, f5, 0, false);
          d1     = __builtin_amdgcn_cvt_pk_fp8_f32(f6, f7, d1, true);
          *reinterpret_cast<uint2*>(Y8 + (size_t)node*128 + cl*8) = make_uint2((uint)d0, (uint)d1);
        } else {
          if (ct == 0 || ct == 3){
            ushort* Y = (ct == 0) ? (ushort*)Yq : Ysk;
            ushort* yr = Y + (size_t)node*128 + cl;
            #pragma unroll
            for (int cf=0;cf<8;++cf)
              yr[cf*16] = bf16bits(acc[cf][j] + bias[ct*128 + cf*16 + cl]);
          } else {
            #pragma unroll
            for (int g=0; g<2; ++g){
              float f0 = (acc[g*4+0][j] + bias[ct*128 + (g*4+0)*16 + cl])*16.f;
              float f1 = (acc[g*4+1][j] + bias[ct*128 + (g*4+1)*16 + cl])*16.f;
              float f2 = (acc[g*4+2][j] + bias[ct*128 + (g*4+2)*16 + cl])*16.f;
              float f3 = (acc[g*4+3][j] + bias[ct*128 + (g*4+3)*16 + cl])*16.f;
              int d = __builtin_amdgcn_cvt_pk_fp8_f32(f0, f1, 0, false);
              d     = __builtin_amdgcn_cvt_pk_fp8_f32(f2, f3, d, true);
              int m = cl + 16*((ct-1)*2 + g);
              Ykv[(size_t)node*64 + m] = (uint)d;
            }
          }
        }
      }
    }
  }
}

// ---------------- attention scalars from fp8 permuted hw ----------------
__global__ __launch_bounds__(256) void k_att(const unsigned char* __restrict__ hw8,
        const float* __restrict__ attS, const float* __restrict__ attD,
        float* __restrict__ a_s, float* __restrict__ a_d, int n){
  int wv = threadIdx.x>>6, l = threadIdx.x&63;
  int node = blockIdx.x*4 + wv; if (node>=n) return;
  int hh = l & 3;
  int c0 = 32*hh + (l>>2), c1 = c0 + 16;
  uint us = reinterpret_cast<const ushort*>(hw8 + (size_t)node*128)[l];
  f32x2 f = __builtin_amdgcn_cvt_pk_f32_fp8((int)us, false);
  float ps = f.x*attS[c0] + f.y*attS[c1];
  float pd = f.x*attD[c0] + f.y*attD[c1];
  #pragma unroll
  for (int m=4;m<64;m<<=1){ ps += __shfl_xor(ps,m); pd += __shfl_xor(pd,m); }
  if (l < 4){
    a_s[(size_t)node*4 + hh] = ps * (1.f/16.f);
    a_d[(size_t)node*4 + hh] = pd * (1.f/16.f);
  }
}

// ---------------- GAT aggregate: chunked LDS weight precompute ----------------
__global__ __launch_bounds__(256) void k_gat_agg(const int* __restrict__ rowstart, const ushort* __restrict__ csr16,
              const unsigned char* __restrict__ hw8, const float* __restrict__ a_src,
              const float* __restrict__ a_dst, const float* __restrict__ bias,
              float* __restrict__ h, ushort* __restrict__ hb, int n){
  __shared__ float4 lw[4][64];
  __shared__ ushort lsrc[4][64];
  int wv = threadIdx.x >> 6, l = threadIdx.x & 63;
  int node = blockIdx.x*4 + wv;
  if (node >= n) return;
  int hh = l & 3;
  int c0 = 32*hh + (l>>2), c1 = c0 + 16;
  int start = rowstart[node], end = rowstart[node+1];
  float4 ad4 = *reinterpret_cast<const float4*>(a_dst + (size_t)node*4);
  const ushort* rows = reinterpret_cast<const ushort*>(hw8);

  // self-loop handled analytically (not in CSR)
  float ssc = a_src[(size_t)node*4 + hh] + a_dst[(size_t)node*4 + hh];
  ssc = fmaxf(ssc, 0.2f*ssc);
  float s = __expf(fminf(ssc, 30.f));
  f32x2 fs = __builtin_amdgcn_cvt_pk_f32_fp8((int)(uint)rows[(size_t)node*64 + l], false);
  float ax = s*fs.x, ay = s*fs.y;

  const float* lwf = reinterpret_cast<const float*>(&lw[wv][0]);
  for (int base = start; base < end; base += 64){
    int len = end - base; len = len > 64 ? 64 : len;
    if (l < len){
      int sv = csr16[base + l];
      lsrc[wv][l] = (ushort)sv;
      float4 a4 = *reinterpret_cast<const float4*>(a_src + (size_t)sv*4);
      float s0 = a4.x + ad4.x; s0 = fmaxf(s0, 0.2f*s0);
      float s1 = a4.y + ad4.y; s1 = fmaxf(s1, 0.2f*s1);
      float s2 = a4.z + ad4.z; s2 = fmaxf(s2, 0.2f*s2);
      float s3 = a4.w + ad4.w; s3 = fmaxf(s3, 0.2f*s3);
      float4 w4;
      w4.x = __expf(fminf(s0,30.f));
      w4.y = __expf(fminf(s1,30.f));
      w4.z = __expf(fminf(s2,30.f));
      w4.w = __expf(fminf(s3,30.f));
      lw[wv][l] = w4;
    }
    int p = 0;
    for (; p+1 < len; p += 2){
      int e0 = lsrc[wv][p], e1 = lsrc[wv][p+1];
      float w0 = lwf[p*4 + hh], w1 = lwf[(p+1)*4 + hh];
      uint u0 = rows[(size_t)e0*64 + l];
      uint u1 = rows[(size_t)e1*64 + l];
      f32x2 f0 = __builtin_amdgcn_cvt_pk_f32_fp8((int)u0, false);
      f32x2 f1 = __builtin_amdgcn_cvt_pk_f32_fp8((int)u1, false);
      s  += w0 + w1;
      ax += w0*f0.x + w1*f1.x;
      ay += w0*f0.y + w1*f1.y;
    }
    if (p < len){
      int e0 = lsrc[wv][p];
      float w0 = lwf[p*4 + hh];
      f32x2 f0 = __builtin_amdgcn_cvt_pk_f32_fp8((int)(uint)rows[(size_t)e0*64 + l], false);
      s += w0; ax += w0*f0.x; ay += w0*f0.y;
    }
  }
  float inv = 1.f/(s + 1e-16f);
  float ox = ax*inv*(1.f/16.f) + bias[c0];
  float oy = ay*inv*(1.f/16.f) + bias[c1];
  ox = ox > 0.f ? ox : (__expf(ox)-1.f);
  oy = oy > 0.f ? oy : (__expf(oy)-1.f);
  float hx = h[(size_t)node*128 + c0] + ox;
  float hy = h[(size_t)node*128 + c1] + oy;
  h[(size_t)node*128 + c0] = hx;
  h[(size_t)node*128 + c1] = hy;
  hb[(size_t)node*128 + c0] = bf16bits(hx);
  hb[(size_t)node*128 + c1] = bf16bits(hy);
}

// ---------------- transformer aggregate + fused layernorm ----------------
__global__ __launch_bounds__(256) void k_trans_agg(const int* __restrict__ rowstart, const ushort* __restrict__ csr16,
              const ushort* __restrict__ yq, const uint* __restrict__ ykv,
              const ushort* __restrict__ ysk, const float* __restrict__ lng,
              const float* __restrict__ lnb, float* __restrict__ h, int n){
  int wv = threadIdx.x>>6, lane = threadIdx.x&63;
  int node = blockIdx.x*4 + wv;
  if (node >= n) return;
  int li = lane & 15;
  bool odd1 = li & 1, odd2 = li & 2;
  const uint* q32 = reinterpret_cast<const uint*>(yq);
  const uint* s32 = reinterpret_cast<const uint*>(ysk);
  float2 q2 = bf2_to_f2(q32[(size_t)node*64 + lane]);   // q pre-scaled by 1/(sqrt(32)*16)
  int start = rowstart[node], end = rowstart[node+1];
  float s = 0.f, s_tail = 0.f, ax = 0.f, ay = 0.f;
  int p = start;
  for (; p+3 < end; p += 4){
    int i0 = csr16[p], i1 = csr16[p+1], i2 = csr16[p+2], i3 = csr16[p+3];
    uint u0 = ykv[(size_t)i0*64 + lane];
    uint u1 = ykv[(size_t)i1*64 + lane];
    uint u2 = ykv[(size_t)i2*64 + lane];
    uint u3 = ykv[(size_t)i3*64 + lane];
    f32x2 k0 = __builtin_amdgcn_cvt_pk_f32_fp8((int)u0, false);
    f32x2 k1 = __builtin_amdgcn_cvt_pk_f32_fp8((int)u1, false);
    f32x2 k2 = __builtin_amdgcn_cvt_pk_f32_fp8((int)u2, false);
    f32x2 k3 = __builtin_amdgcn_cvt_pk_f32_fp8((int)u3, false);
    float p0 = q2.x*k0.x + q2.y*k0.y;
    float p1 = q2.x*k1.x + q2.y*k1.y;
    float p2 = q2.x*k2.x + q2.y*k2.y;
    float p3 = q2.x*k3.x + q2.y*k3.y;
    float a = (odd1 ? p1 : p0) + __shfl_xor(odd1 ? p0 : p1, 1);
    float b = (odd1 ? p3 : p2) + __shfl_xor(odd1 ? p2 : p3, 1);
    float c = (odd2 ? b : a) + __shfl_xor(odd2 ? a : b, 2);
    c += __shfl_xor(c, 4);
    c += __shfl_xor(c, 8);
    float w = __expf(fminf(c, 30.f));
    s += w;
    float g1 = __shfl_xor(w, 1);
    float g2 = __shfl_xor(w, 2);
    float g3 = __shfl_xor(g1, 2);
    float A = odd2 ? g3 : g1;
    float B = odd2 ? g2 : w;
    float C = odd2 ? g1 : g3;
    float D = odd2 ? w  : g2;
    float w0 = odd1 ? A : B;
    float w1 = odd1 ? B : A;
    float w2 = odd1 ? C : D;
    float w3 = odd1 ? D : C;
    f32x2 v0 = __builtin_amdgcn_cvt_pk_f32_fp8((int)u0, true);
    f32x2 v1 = __builtin_amdgcn_cvt_pk_f32_fp8((int)u1, true);
    f32x2 v2 = __builtin_amdgcn_cvt_pk_f32_fp8((int)u2, true);
    f32x2 v3 = __builtin_amdgcn_cvt_pk_f32_fp8((int)u3, true);
    ax += w0*v0.x + w1*v1.x + w2*v2.x + w3*v3.x;
    ay += w0*v0.y + w1*v1.y + w2*v2.y + w3*v3.y;
  }
  for (; p < end; ++p){
    int idx = csr16[p];
    uint u = ykv[(size_t)idx*64 + lane];
    f32x2 k2 = __builtin_amdgcn_cvt_pk_f32_fp8((int)u, false);
    float pr = q2.x*k2.x + q2.y*k2.y;
    pr += __shfl_xor(pr,1); pr += __shfl_xor(pr,2);
    pr += __shfl_xor(pr,4); pr += __shfl_xor(pr,8);
    float wt = __expf(fminf(pr, 30.f));
    f32x2 v2 = __builtin_amdgcn_cvt_pk_f32_fp8((int)u, true);
    s_tail += wt; ax += wt*v2.x; ay += wt*v2.y;
  }
  s += __shfl_xor(s, 1);
  s += __shfl_xor(s, 2);
  s += s_tail;
  float inv = (1.f/16.f)/(s + 1e-16f);       // fold out v's x16 scale
  int d = lane*2;
  float2 sk = bf2_to_f2(s32[(size_t)node*64 + lane]);
  float tx = ax*inv + sk.x;
  float ty = ay*inv + sk.y;
  tx = tx>0.f?tx:(__expf(tx)-1.f);
  ty = ty>0.f?ty:(__expf(ty)-1.f);
  float2 hp = *reinterpret_cast<const float2*>(h + (size_t)node*128 + d);
  hp.x += tx; hp.y += ty;
  // fused layernorm
  float sm = hp.x + hp.y;
  #pragma unroll
  for (int m=1;m<64;m<<=1) sm += __shfl_xor(sm,m);
  float mu = sm * (1.f/128.f);
  float dx = hp.x-mu, dy = hp.y-mu;
  float vs = dx*dx + dy*dy;
  #pragma unroll
  for (int m=1;m<64;m<<=1) vs += __shfl_xor(vs,m);
  float r = rsqrtf(vs*(1.f/128.f) + 1e-5f);
  float2 gg = *reinterpret_cast<const float2*>(lng+d);
  float2 bb = *reinterpret_cast<const float2*>(lnb+d);
  hp.x = dx*r*gg.x + bb.x;
  hp.y = dy*r*gg.y + bb.y;
  *reinterpret_cast<float2*>(h + (size_t)node*128 + d) = hp;
}

// ---------------- pooling ----------------
__global__ void k_gbounds(const int* __restrict__ batch, int* __restrict__ gb, int n, int G){
  int g = blockIdx.x*blockDim.x + threadIdx.x;
  if (g > G) return;
  int lo=0, hi=n;
  while (lo<hi){ int mid=(lo+hi)>>1; if (batch[mid] < g) lo=mid+1; else hi=mid; }
  gb[g] = lo;
}

__global__ void k_pool(const float* __restrict__ hln, const int* __restrict__ gb,
                       float* __restrict__ out, int G){
  int g = blockIdx.x, d = threadIdx.x;   // 128 threads
  int s = gb[g], e = gb[g+1];
  float acc = 0.f;
  for (int i=s;i<e;++i) acc += hln[(size_t)i*128 + d];
  out[(size_t)g*128 + d] = acc / fmaxf((float)(e-s), 1.f);
}

// ---------------- launch ----------------
extern "C" void kernel_launch(void* const* d_in, const int* in_sizes, int n_in,
                              void* d_out, int out_size, void* d_ws, size_t ws_size,
                              hipStream_t stream){
  const int* xn    = (const int*)d_in[0];
  const int* ei    = (const int*)d_in[1];
  const int* batch = (const int*)d_in[2];
  const float* emb  = (const float*)d_in[4];
  const float* demb = (const float*)d_in[5];
  const float* projW= (const float*)d_in[6];
  const float* projB= (const float*)d_in[7];
  const float* gatW = (const float*)d_in[8];
  const float* attS = (const float*)d_in[9];
  const float* attD = (const float*)d_in[10];
  const float* gatB = (const float*)d_in[11];
  const float* Wq = (const float*)d_in[12];
  const float* bq = (const float*)d_in[13];
  const float* Wk = (const float*)d_in[14];
  const float* bk = (const float*)d_in[15];
  const float* Wv = (const float*)d_in[16];
  const float* bv = (const float*)d_in[17];
  const float* Wsk= (const float*)d_in[18];
  const float* bsk= (const float*)d_in[19];
  const float* lng= (const float*)d_in[20];
  const float* lnb= (const float*)d_in[21];
  float* out = (float*)d_out;

  int N = in_sizes[0]/2;
  int E = in_sizes[1]/2;
  int G = out_size/128;

  char* w = (char*)d_ws;
  size_t off = 0;
  auto alloc = [&](size_t bytes)->char*{ char* p = w+off; off += (bytes + 255) & ~(size_t)255; return p; };
  float*  h    = (float*) alloc((size_t)N*128*4);
  ushort* hb   = (ushort*)alloc((size_t)N*128*2);
  ushort* yq   = (ushort*)alloc((size_t)N*128*2);   // q bf16; fp8 hw aliases its front half
  uint*   ykv  = (uint*)  alloc((size_t)N*64*4);    // fp8 kv quads
  ushort* ysk  = (ushort*)alloc((size_t)N*128*2);   // skip bf16
  unsigned char* hw8 = (unsigned char*)yq;
  float* a_s  = (float*)alloc((size_t)N*4*4);
  float* a_d  = (float*)alloc((size_t)N*4*4);
  int* cnt    = (int*)alloc((size_t)N*4);
  int* rowstart=(int*)alloc((size_t)(N+1)*4);
  int* rank   = (int*)alloc((size_t)E*4);
  ushort* csr16 = (ushort*)alloc((size_t)E*2);
  int* bsum   = (int*)alloc(4096);
  int* gb     = (int*)alloc((size_t)(G+1)*4);
  float* table= (float*)alloc(180*128*4);
  ushort* wt_gat  = (ushort*)alloc((size_t)3*128*128*2);
  ushort* wt_qkvs = (ushort*)alloc((size_t)512*128*2);
  float* bias512  = (float*)alloc(512*4);
  (void)ws_size; (void)n_in;

  int nb = (N+255)/256;

  k_zero1<<<(N+255)/256,256,0,stream>>>(cnt, N);
  k_table<<<180,128,0,stream>>>(emb, demb, projW, projB, table);
  k_init_h<<<(N*64+255)/256,256,0,stream>>>(xn, table, h, hb, N);
  k_rank<<<(E+255)/256,256,0,stream>>>(ei, cnt, rank, E);
  k_scan_block<<<nb,256,0,stream>>>(cnt, rowstart, bsum, N);
  k_scan_sums<<<1,256,0,stream>>>(bsum, nb);
  k_scan_add<<<nb,256,0,stream>>>(rowstart, bsum, N, E);
  k_place<<<(E+255)/256,256,0,stream>>>(ei, rowstart, rank, csr16, E);
  k_prep_wt_gat<<<192,256,0,stream>>>(gatW, wt_gat);
  k_prep_wt_qkvs<<<256,256,0,stream>>>(Wq, Wk, Wv, Wsk, bq, bk, bv, bsk, wt_qkvs, bias512);

  int gemm_grid = (N+63)/64;
  for (int l=0;l<3;++l){
    k_gemm_mfma<1,1><<<gemm_grid,256,0,stream>>>(hb, wt_gat + (size_t)l*16384, nullptr,
                                                 hw8, nullptr, nullptr, N);
    k_att<<<(N+3)/4,256,0,stream>>>(hw8, attS + l*128, attD + l*128, a_s, a_d, N);
    k_gat_agg<<<(N+3)/4,256,0,stream>>>(rowstart, csr16, hw8, a_s, a_d, gatB + l*128, h, hb, N);
  }

  k_gemm_mfma<4,2><<<gemm_grid,256,0,stream>>>(hb, wt_qkvs, bias512, yq, ykv, ysk, N);
  k_trans_agg<<<(N+3)/4,256,0,stream>>>(rowstart, csr16, yq, ykv, ysk, lng, lnb, h, N);

  k_gbounds<<<(G+256)/256,256,0,stream>>>(batch, gb, N, G);
  k_pool<<<G,128,0,stream>>>(h, gb, out, G);
}

// Round 6
// 452.453 us; speedup vs baseline: 3.6538x; 1.1404x over previous
//
#include <hip/hip_runtime.h>
#include <hip/hip_bf16.h>

typedef unsigned int uint;
typedef unsigned short ushort;
typedef __attribute__((ext_vector_type(8))) short bf16x8;
typedef __attribute__((ext_vector_type(4))) float f32x4;
typedef __attribute__((ext_vector_type(2))) float f32x2;

__device__ __forceinline__ float2 bf2_to_f2(uint u){
  union {unsigned int i; float f;} a,b;
  a.i = (u & 0xffffu) << 16;
  b.i = u & 0xffff0000u;
  return make_float2(a.f, b.f);
}
__device__ __forceinline__ float b2f(ushort u){
  union{uint i; float f;} x; x.i = (uint)u << 16; return x.f;
}
__device__ __forceinline__ ushort bf16bits(float f){
  union{ __hip_bfloat16 h; ushort u;} x; x.h = __float2bfloat16(f); return x.u;
}
__device__ __forceinline__ uint pack_bf2(float x, float y){
  return ((uint)bf16bits(y)<<16) | (uint)bf16bits(x);
}

// ---------------- init / CSR build ----------------

__global__ void k_zero1(int* a, int n){
  int i = blockIdx.x*blockDim.x + threadIdx.x;
  if (i < n) a[i] = 0;
}

// h0 = concat(emb[a], depth_emb[b]) @ projW + projB : only 9*20=180 combos
__global__ void k_table(const float* __restrict__ emb, const float* __restrict__ demb,
                        const float* __restrict__ W, const float* __restrict__ bias,
                        float* __restrict__ table){
  int d = threadIdx.x;          // 128
  int combo = blockIdx.x;       // 180
  int a = combo/20, b = combo - a*20;
  float acc = bias[d];
  #pragma unroll 8
  for (int i=0;i<32;++i) acc += emb[a*32+i]*W[i*128+d];
  #pragma unroll 8
  for (int i=0;i<32;++i) acc += demb[b*32+i]*W[(32+i)*128+d];
  table[combo*128+d] = acc;
}

__global__ void k_init_h(const int* __restrict__ xn, const float* __restrict__ table,
                         ushort* __restrict__ hb, int n){
  int gid = blockIdx.x*blockDim.x + threadIdx.x;
  if (gid >= n*64) return;
  int node = gid >> 6, lp = gid & 63;
  int x0 = xn[2*node];
  int x1 = xn[2*node+1]; x1 = x1<0?0:(x1>19?19:x1);
  const float* tr = table + (size_t)(x0*20+x1)*128 + lp*2;
  reinterpret_cast<uint*>(hb)[(size_t)node*64 + lp] = pack_bf2(tr[0], tr[1]);
}

// rank[e] = arrival index within dst row; cnt accumulates degree (real edges only)
__global__ void k_rank(const int* __restrict__ ei, int* __restrict__ cnt,
                       int* __restrict__ rank, int E){
  int e = blockIdx.x*blockDim.x + threadIdx.x;
  if (e >= E) return;
  rank[e] = atomicAdd(&cnt[ei[E+e]], 1);
}

__global__ __launch_bounds__(256) void k_scan_block(const int* __restrict__ deg, int* __restrict__ rowstart,
                                                    int* __restrict__ bsum, int n){
  int tid = threadIdx.x;
  int gid = blockIdx.x*256 + tid;
  int lane = tid & 63, wv = tid >> 6;
  int v = (gid < n) ? deg[gid] : 0;
  int x = v;
  #pragma unroll
  for (int off=1; off<64; off<<=1){
    int t = __shfl_up(x, off);
    if (lane >= off) x += t;
  }
  __shared__ int wsum[4], woff[4];
  if (lane==63) wsum[wv] = x;
  __syncthreads();
  if (tid==0){
    int r = 0;
    for (int i=0;i<4;++i){ woff[i]=r; r += wsum[i]; }
    bsum[blockIdx.x] = r;
  }
  __syncthreads();
  if (gid < n) rowstart[gid] = x + woff[wv] - v;
}

__global__ __launch_bounds__(256) void k_scan_sums(int* __restrict__ bsum, int nb){
  int tid = threadIdx.x;
  int lane = tid&63, wv = tid>>6;
  int v = (tid<nb)?bsum[tid]:0;
  int x = v;
  #pragma unroll
  for (int off=1;off<64;off<<=1){ int t=__shfl_up(x,off); if(lane>=off) x+=t; }
  __shared__ int wsum[4], woff[4];
  if (lane==63) wsum[wv]=x;
  __syncthreads();
  if (tid==0){ int r=0; for(int i=0;i<4;++i){woff[i]=r;r+=wsum[i];} }
  __syncthreads();
  if (tid<nb) bsum[tid] = x + woff[wv] - v;
}

__global__ void k_scan_add(int* __restrict__ rowstart, const int* __restrict__ bsum, int n, int total){
  int gid = blockIdx.x*256 + threadIdx.x;
  if (gid < n) rowstart[gid] += bsum[blockIdx.x];
  if (gid == 0) rowstart[n] = total;
}

__global__ void k_place(const int* __restrict__ ei, const int* __restrict__ rowstart,
                        const int* __restrict__ rank, ushort* __restrict__ csr16, int E){
  int e = blockIdx.x*blockDim.x + threadIdx.x;
  if (e >= E) return;
  csr16[rowstart[ei[E+e]] + rank[e]] = (ushort)ei[e];
}

// ---------------- weight prep ----------------

// wt_gat: per layer 144 cols x 128 k. Cols 0..127: transposed gatW.
__global__ void k_prep_wt_gat(const float* __restrict__ gatW, ushort* __restrict__ wt){
  int i = blockIdx.x*256 + threadIdx.x;   // < 3*128*128
  int l = i >> 14, rem = i & 16383, c = rem >> 7, k = rem & 127;
  wt[(size_t)l*18432 + c*128 + k] = bf16bits(gatW[l*16384 + k*128 + c]);
}

// Cols 128..143: combined attention vectors. col 128+i: i<4 -> a_s head i = W@attS_h;
// i in 4..7 -> a_d head i-4; i>=8 -> zero.
__global__ void k_prep_wt_gatt(const float* __restrict__ gatW, const float* __restrict__ attS,
                               const float* __restrict__ attD, ushort* __restrict__ wt){
  int l = blockIdx.x >> 4, i = blockIdx.x & 15, k = threadIdx.x;  // 48 blocks x 128
  float acc = 0.f;
  if (i < 8){
    int sd = i >> 2, hh = i & 3;
    const float* att = (sd ? attD : attS) + l*128 + hh*32;
    #pragma unroll 8
    for (int c=0;c<32;++c) acc += gatW[l*16384 + k*128 + hh*32 + c] * att[c];
  }
  wt[(size_t)l*18432 + (128+i)*128 + k] = bf16bits(acc);
}

// fused q | kv(fp8-quad permuted) | skip. GEMM col c -> canonical source col:
//  c in [0,128):   q col c, scaled 1/(sqrt(32)*16)  (absorbs k's x16 fp8 scale)
//  c in [128,384): ct=c>>7, cf=(c&127)>>4, cl=c&15; m=cl+16*((ct-1)*2+(cf>>2)); wn=cf&3
//                  wn<2 -> k col 2m+wn ; else v col 2m+wn-2
//  c in [384,512): skip col c-384
__global__ void k_prep_wt_qkvs(const float* __restrict__ Wq, const float* __restrict__ Wk,
                               const float* __restrict__ Wv, const float* __restrict__ Ws,
                               const float* __restrict__ bq, const float* __restrict__ bk,
                               const float* __restrict__ bv, const float* __restrict__ bs,
                               ushort* __restrict__ wt, float* __restrict__ bias){
  int i = blockIdx.x*256 + threadIdx.x;   // < 512*128
  int c = i >> 7, k = i & 127;
  const float* W; const float* B; int sc; float scale = 1.f;
  if (c < 128){ W = Wq; B = bq; sc = c; scale = 0.011048543456039805f; } // 1/(sqrt(32)*16)
  else if (c < 384){
    int ct = c >> 7, within = c & 127, cf = within >> 4, cl = within & 15;
    int m = cl + 16*((ct-1)*2 + (cf>>2));
    int wn = cf & 3;
    if (wn < 2){ W = Wk; B = bk; sc = 2*m + wn; }
    else       { W = Wv; B = bv; sc = 2*m + wn - 2; }
  } else { W = Ws; B = bs; sc = c - 384; }
  wt[c*128 + k] = bf16bits(W[k*128 + sc] * scale);
  if (k == 0) bias[c] = B[sc] * scale;
}

// ---------------- MFMA GEMM ----------------
// MODE 1: CT=1, 144 cols: cf0..7 -> fp8 messages (x16, permuted: byte cl*8+cf = col cf*16+cl);
//         cf8 -> a_sd[node][8] (cl<8).
// MODE 2: CT=4, 128 cols/tile: ct0 -> q bf16, ct1/2 -> kv fp8 quads, ct3 -> skip bf16.
template<int CT, int MODE>
__global__ __launch_bounds__(256) void k_gemm_mfma(const ushort* __restrict__ X,
        const ushort* __restrict__ Wt, const float* __restrict__ bias,
        void* __restrict__ Yq, uint* __restrict__ Ykv, ushort* __restrict__ Ysk,
        float* __restrict__ Asd, int n){
  constexpr int COLS = (MODE==1) ? 144 : 128;
  constexpr int NCF  = COLS/16;
  __shared__ ushort wl[COLS*136];
  const int t = threadIdx.x;
  const int w = t >> 6, lane = t & 63;
  const int cl = lane & 15, khi = lane >> 4;
  const int rbase = blockIdx.x*64;

  int arow = rbase + w*16 + cl; if (arow >= n) arow = n-1;
  const bf16x8* Xr = reinterpret_cast<const bf16x8*>(X + (size_t)arow*128);
  bf16x8 a0 = Xr[0+khi], a1 = Xr[4+khi], a2 = Xr[8+khi], a3 = Xr[12+khi];

  for (int ct=0; ct<CT; ++ct){
    const ushort* wsrc = Wt + (size_t)ct*16384;
    __syncthreads();
    for (int idx = t; idx < COLS*2; idx += 256){
      int col = idx >> 1, k0 = (idx & 1)*64;
      const bf16x8* src = reinterpret_cast<const bf16x8*>(wsrc + (size_t)col*128 + k0);
      bf16x8* dst = reinterpret_cast<bf16x8*>(wl + col*136 + k0);
      #pragma unroll
      for (int i=0;i<8;++i) dst[i] = src[i];
    }
    __syncthreads();

    f32x4 acc[NCF];
    #pragma unroll
    for (int cf=0;cf<NCF;++cf) acc[cf] = f32x4{0.f,0.f,0.f,0.f};

    #pragma unroll
    for (int ks=0; ks<4; ++ks){
      bf16x8 av = (ks==0)?a0:(ks==1)?a1:(ks==2)?a2:a3;
      #pragma unroll
      for (int cf=0; cf<NCF; ++cf){
        bf16x8 bv = *reinterpret_cast<const bf16x8*>(wl + (cf*16+cl)*136 + ks*32 + khi*8);
        acc[cf] = __builtin_amdgcn_mfma_f32_16x16x32_bf16(av, bv, acc[cf], 0, 0, 0);
      }
    }

    #pragma unroll
    for (int j=0;j<4;++j){
      int node = rbase + w*16 + khi*4 + j;
      if (node < n){
        if (MODE==1){
          unsigned char* Y8 = (unsigned char*)Yq;
          float f0 = acc[0][j]*16.f, f1 = acc[1][j]*16.f, f2 = acc[2][j]*16.f, f3 = acc[3][j]*16.f;
          float f4 = acc[4][j]*16.f, f5 = acc[5][j]*16.f, f6 = acc[6][j]*16.f, f7 = acc[7][j]*16.f;
          int d0 = __builtin_amdgcn_cvt_pk_fp8_f32(f0, f1, 0, false);
          d0     = __builtin_amdgcn_cvt_pk_fp8_f32(f2, f3, d0, true);
          int d1 = __builtin_amdgcn_cvt_pk_fp8_f32(f4, f5, 0, false);
          d1     = __builtin_amdgcn_cvt_pk_fp8_f32(f6, f7, d1, true);
          *reinterpret_cast<uint2*>(Y8 + (size_t)node*128 + cl*8) = make_uint2((uint)d0, (uint)d1);
          if (cl < 8) Asd[(size_t)node*8 + cl] = acc[8][j];
        } else {
          if (ct == 0 || ct == 3){
            ushort* Y = (ct == 0) ? (ushort*)Yq : Ysk;
            ushort* yr = Y + (size_t)node*128 + cl;
            #pragma unroll
            for (int cf=0;cf<8;++cf)
              yr[cf*16] = bf16bits(acc[cf][j] + bias[ct*128 + cf*16 + cl]);
          } else {
            #pragma unroll
            for (int g=0; g<2; ++g){
              float f0 = (acc[g*4+0][j] + bias[ct*128 + (g*4+0)*16 + cl])*16.f;
              float f1 = (acc[g*4+1][j] + bias[ct*128 + (g*4+1)*16 + cl])*16.f;
              float f2 = (acc[g*4+2][j] + bias[ct*128 + (g*4+2)*16 + cl])*16.f;
              float f3 = (acc[g*4+3][j] + bias[ct*128 + (g*4+3)*16 + cl])*16.f;
              int d = __builtin_amdgcn_cvt_pk_fp8_f32(f0, f1, 0, false);
              d     = __builtin_amdgcn_cvt_pk_fp8_f32(f2, f3, d, true);
              int m = cl + 16*((ct-1)*2 + g);
              Ykv[(size_t)node*64 + m] = (uint)d;
            }
          }
        }
      }
    }
  }
}

// ---------------- GAT aggregate: chunked LDS weights, 4-edge unroll, bf16 h ----------------
__global__ __launch_bounds__(256) void k_gat_agg(const int* __restrict__ rowstart, const ushort* __restrict__ csr16,
              const unsigned char* __restrict__ hw8, const float* __restrict__ a_sd,
              const float* __restrict__ bias, ushort* __restrict__ hb, int n){
  __shared__ float4 lw[4][64];
  __shared__ ushort lsrc[4][64];
  int wv = threadIdx.x >> 6, l = threadIdx.x & 63;
  int node = blockIdx.x*4 + wv;
  if (node >= n) return;
  int hh = l & 3;
  int c0 = 32*hh + (l>>2), c1 = c0 + 16;
  int start = rowstart[node], end = rowstart[node+1];
  float4 ad4 = *reinterpret_cast<const float4*>(a_sd + (size_t)node*8 + 4);
  float adh = hh==0?ad4.x: hh==1?ad4.y: hh==2?ad4.z: ad4.w;
  const ushort* rows = reinterpret_cast<const ushort*>(hw8);

  // self-loop handled analytically (not in CSR)
  float ssc = a_sd[(size_t)node*8 + hh] + adh;
  ssc = fmaxf(ssc, 0.2f*ssc);
  float s = __expf(fminf(ssc, 30.f));
  f32x2 fs = __builtin_amdgcn_cvt_pk_f32_fp8((int)(uint)rows[(size_t)node*64 + l], false);
  float ax = s*fs.x, ay = s*fs.y;

  const float* lwf = reinterpret_cast<const float*>(&lw[wv][0]);
  for (int base = start; base < end; base += 64){
    int len = end - base; if (len > 64) len = 64;
    if (l < len){
      int sv = csr16[base + l];
      lsrc[wv][l] = (ushort)sv;
      float4 a4 = *reinterpret_cast<const float4*>(a_sd + (size_t)sv*8);
      float s0 = a4.x + ad4.x; s0 = fmaxf(s0, 0.2f*s0);
      float s1 = a4.y + ad4.y; s1 = fmaxf(s1, 0.2f*s1);
      float s2 = a4.z + ad4.z; s2 = fmaxf(s2, 0.2f*s2);
      float s3 = a4.w + ad4.w; s3 = fmaxf(s3, 0.2f*s3);
      float4 w4;
      w4.x = __expf(fminf(s0,30.f));
      w4.y = __expf(fminf(s1,30.f));
      w4.z = __expf(fminf(s2,30.f));
      w4.w = __expf(fminf(s3,30.f));
      lw[wv][l] = w4;
    }
    int p = 0;
    for (; p+3 < len; p += 4){
      int e0 = lsrc[wv][p],   e1 = lsrc[wv][p+1];
      int e2 = lsrc[wv][p+2], e3 = lsrc[wv][p+3];
      float w0 = lwf[p*4+hh],    w1 = lwf[p*4+4+hh];
      float w2 = lwf[p*4+8+hh],  w3 = lwf[p*4+12+hh];
      uint u0 = rows[(size_t)e0*64 + l];
      uint u1 = rows[(size_t)e1*64 + l];
      uint u2 = rows[(size_t)e2*64 + l];
      uint u3 = rows[(size_t)e3*64 + l];
      f32x2 f0 = __builtin_amdgcn_cvt_pk_f32_fp8((int)u0, false);
      f32x2 f1 = __builtin_amdgcn_cvt_pk_f32_fp8((int)u1, false);
      f32x2 f2 = __builtin_amdgcn_cvt_pk_f32_fp8((int)u2, false);
      f32x2 f3 = __builtin_amdgcn_cvt_pk_f32_fp8((int)u3, false);
      s  += (w0+w1)+(w2+w3);
      ax += w0*f0.x + w1*f1.x + w2*f2.x + w3*f3.x;
      ay += w0*f0.y + w1*f1.y + w2*f2.y + w3*f3.y;
    }
    for (; p < len; ++p){
      int e0 = lsrc[wv][p];
      float w0 = lwf[p*4 + hh];
      f32x2 f0 = __builtin_amdgcn_cvt_pk_f32_fp8((int)(uint)rows[(size_t)e0*64 + l], false);
      s += w0; ax += w0*f0.x; ay += w0*f0.y;
    }
  }
  float inv = 1.f/(s + 1e-16f);
  float ox = ax*inv*(1.f/16.f) + bias[c0];
  float oy = ay*inv*(1.f/16.f) + bias[c1];
  ox = ox > 0.f ? ox : (__expf(ox)-1.f);
  oy = oy > 0.f ? oy : (__expf(oy)-1.f);
  float hx = b2f(hb[(size_t)node*128 + c0]) + ox;
  float hy = b2f(hb[(size_t)node*128 + c1]) + oy;
  hb[(size_t)node*128 + c0] = bf16bits(hx);
  hb[(size_t)node*128 + c1] = bf16bits(hy);
}

// ---------------- transformer aggregate + fused layernorm (bf16 h) ----------------
__global__ __launch_bounds__(256) void k_trans_agg(const int* __restrict__ rowstart, const ushort* __restrict__ csr16,
              const ushort* __restrict__ yq, const uint* __restrict__ ykv,
              const ushort* __restrict__ ysk, const float* __restrict__ lng,
              const float* __restrict__ lnb, ushort* __restrict__ hb, int n){
  int wv = threadIdx.x>>6, lane = threadIdx.x&63;
  int node = blockIdx.x*4 + wv;
  if (node >= n) return;
  int li = lane & 15;
  bool odd1 = li & 1, odd2 = li & 2;
  int lbase = lane & 48;
  const uint* q32 = reinterpret_cast<const uint*>(yq);
  const uint* s32 = reinterpret_cast<const uint*>(ysk);
  uint* h32 = reinterpret_cast<uint*>(hb);
  float2 q2 = bf2_to_f2(q32[(size_t)node*64 + lane]);   // q pre-scaled by 1/(sqrt(32)*16)
  int start = rowstart[node], end = rowstart[node+1];
  float s = 0.f, s_tail = 0.f, ax = 0.f, ay = 0.f;
  int p = start;
  for (; p+3 < end; p += 4){
    int i0 = csr16[p], i1 = csr16[p+1], i2 = csr16[p+2], i3 = csr16[p+3];
    uint u0 = ykv[(size_t)i0*64 + lane];
    uint u1 = ykv[(size_t)i1*64 + lane];
    uint u2 = ykv[(size_t)i2*64 + lane];
    uint u3 = ykv[(size_t)i3*64 + lane];
    f32x2 k0 = __builtin_amdgcn_cvt_pk_f32_fp8((int)u0, false);
    f32x2 k1 = __builtin_amdgcn_cvt_pk_f32_fp8((int)u1, false);
    f32x2 k2 = __builtin_amdgcn_cvt_pk_f32_fp8((int)u2, false);
    f32x2 k3 = __builtin_amdgcn_cvt_pk_f32_fp8((int)u3, false);
    float p0 = q2.x*k0.x + q2.y*k0.y;
    float p1 = q2.x*k1.x + q2.y*k1.y;
    float p2 = q2.x*k2.x + q2.y*k2.y;
    float p3 = q2.x*k3.x + q2.y*k3.y;
    float a = (odd1 ? p1 : p0) + __shfl_xor(odd1 ? p0 : p1, 1);
    float b = (odd1 ? p3 : p2) + __shfl_xor(odd1 ? p2 : p3, 1);
    float c = (odd2 ? b : a) + __shfl_xor(odd2 ? a : b, 2);
    c += __shfl_xor(c, 4);
    c += __shfl_xor(c, 8);
    float w = __expf(fminf(c, 30.f));   // lane li owns edge li&3
    s += w;
    float w0 = __shfl(w, lbase);
    float w1 = __shfl(w, lbase|1);
    float w2 = __shfl(w, lbase|2);
    float w3 = __shfl(w, lbase|3);
    f32x2 v0 = __builtin_amdgcn_cvt_pk_f32_fp8((int)u0, true);
    f32x2 v1 = __builtin_amdgcn_cvt_pk_f32_fp8((int)u1, true);
    f32x2 v2 = __builtin_amdgcn_cvt_pk_f32_fp8((int)u2, true);
    f32x2 v3 = __builtin_amdgcn_cvt_pk_f32_fp8((int)u3, true);
    ax += w0*v0.x + w1*v1.x + w2*v2.x + w3*v3.x;
    ay += w0*v0.y + w1*v1.y + w2*v2.y + w3*v3.y;
  }
  for (; p < end; ++p){
    int idx = csr16[p];
    uint u = ykv[(size_t)idx*64 + lane];
    f32x2 k2 = __builtin_amdgcn_cvt_pk_f32_fp8((int)u, false);
    float pr = q2.x*k2.x + q2.y*k2.y;
    pr += __shfl_xor(pr,1); pr += __shfl_xor(pr,2);
    pr += __shfl_xor(pr,4); pr += __shfl_xor(pr,8);
    float wt = __expf(fminf(pr, 30.f));
    f32x2 v2 = __builtin_amdgcn_cvt_pk_f32_fp8((int)u, true);
    s_tail += wt; ax += wt*v2.x; ay += wt*v2.y;
  }
  s += __shfl_xor(s, 1);
  s += __shfl_xor(s, 2);
  s += s_tail;
  float inv = (1.f/16.f)/(s + 1e-16f);       // fold out v's x16 scale
  int d = lane*2;
  float2 sk = bf2_to_f2(s32[(size_t)node*64 + lane]);
  float tx = ax*inv + sk.x;
  float ty = ay*inv + sk.y;
  tx = tx>0.f?tx:(__expf(tx)-1.f);
  ty = ty>0.f?ty:(__expf(ty)-1.f);
  float2 hp = bf2_to_f2(h32[(size_t)node*64 + lane]);
  hp.x += tx; hp.y += ty;
  // fused layernorm
  float sm = hp.x + hp.y;
  #pragma unroll
  for (int m=1;m<64;m<<=1) sm += __shfl_xor(sm,m);
  float mu = sm * (1.f/128.f);
  float dx = hp.x-mu, dy = hp.y-mu;
  float vs = dx*dx + dy*dy;
  #pragma unroll
  for (int m=1;m<64;m<<=1) vs += __shfl_xor(vs,m);
  float r = rsqrtf(vs*(1.f/128.f) + 1e-5f);
  float2 gg = *reinterpret_cast<const float2*>(lng+d);
  float2 bb = *reinterpret_cast<const float2*>(lnb+d);
  h32[(size_t)node*64 + lane] = pack_bf2(dx*r*gg.x + bb.x, dy*r*gg.y + bb.y);
}

// ---------------- pooling (fused bounds search) ----------------
__global__ void k_pool(const ushort* __restrict__ hb, const int* __restrict__ batch,
                       float* __restrict__ out, int n, int G){
  int g = blockIdx.x, t = threadIdx.x;   // 64 threads
  int lo=0, hi=n;
  while (lo<hi){ int m=(lo+hi)>>1; if (batch[m] < g) lo=m+1; else hi=m; }
  int s = lo;
  lo=s; hi=n;
  while (lo<hi){ int m=(lo+hi)>>1; if (batch[m] < g+1) lo=m+1; else hi=m; }
  int e = lo;
  const uint* rows = reinterpret_cast<const uint*>(hb);
  float ax=0.f, ay=0.f;
  for (int i=s;i<e;++i){
    float2 f = bf2_to_f2(rows[(size_t)i*64 + t]);
    ax += f.x; ay += f.y;
  }
  float invc = 1.f / fmaxf((float)(e-s), 1.f);
  out[(size_t)g*128 + 2*t]   = ax*invc;
  out[(size_t)g*128 + 2*t+1] = ay*invc;
}

// ---------------- launch ----------------
extern "C" void kernel_launch(void* const* d_in, const int* in_sizes, int n_in,
                              void* d_out, int out_size, void* d_ws, size_t ws_size,
                              hipStream_t stream){
  const int* xn    = (const int*)d_in[0];
  const int* ei    = (const int*)d_in[1];
  const int* batch = (const int*)d_in[2];
  const float* emb  = (const float*)d_in[4];
  const float* demb = (const float*)d_in[5];
  const float* projW= (const float*)d_in[6];
  const float* projB= (const float*)d_in[7];
  const float* gatW = (const float*)d_in[8];
  const float* attS = (const float*)d_in[9];
  const float* attD = (const float*)d_in[10];
  const float* gatB = (const float*)d_in[11];
  const float* Wq = (const float*)d_in[12];
  const float* bq = (const float*)d_in[13];
  const float* Wk = (const float*)d_in[14];
  const float* bk = (const float*)d_in[15];
  const float* Wv = (const float*)d_in[16];
  const float* bv = (const float*)d_in[17];
  const float* Wsk= (const float*)d_in[18];
  const float* bsk= (const float*)d_in[19];
  const float* lng= (const float*)d_in[20];
  const float* lnb= (const float*)d_in[21];
  float* out = (float*)d_out;

  int N = in_sizes[0]/2;
  int E = in_sizes[1]/2;
  int G = out_size/128;

  char* w = (char*)d_ws;
  size_t off = 0;
  auto alloc = [&](size_t bytes)->char*{ char* p = w+off; off += (bytes + 255) & ~(size_t)255; return p; };
  ushort* hb   = (ushort*)alloc((size_t)N*128*2);   // h lives only as bf16
  ushort* yq   = (ushort*)alloc((size_t)N*128*2);   // q bf16; fp8 hw aliases its front half
  uint*   ykv  = (uint*)  alloc((size_t)N*64*4);    // fp8 kv quads
  ushort* ysk  = (ushort*)alloc((size_t)N*128*2);   // skip bf16
  unsigned char* hw8 = (unsigned char*)yq;
  float* a_sd = (float*)alloc((size_t)N*8*4);       // [node][a_s h0..3 | a_d h0..3]
  int* cnt    = (int*)alloc((size_t)N*4);
  int* rowstart=(int*)alloc((size_t)(N+1)*4);
  int* rank   = (int*)alloc((size_t)E*4);
  ushort* csr16 = (ushort*)alloc((size_t)E*2);
  int* bsum   = (int*)alloc(4096);
  float* table= (float*)alloc(180*128*4);
  ushort* wt_gat  = (ushort*)alloc((size_t)3*144*128*2);
  ushort* wt_qkvs = (ushort*)alloc((size_t)512*128*2);
  float* bias512  = (float*)alloc(512*4);
  (void)ws_size; (void)n_in;

  int nb = (N+255)/256;

  k_zero1<<<(N+255)/256,256,0,stream>>>(cnt, N);
  k_table<<<180,128,0,stream>>>(emb, demb, projW, projB, table);
  k_init_h<<<(N*64+255)/256,256,0,stream>>>(xn, table, hb, N);
  k_rank<<<(E+255)/256,256,0,stream>>>(ei, cnt, rank, E);
  k_scan_block<<<nb,256,0,stream>>>(cnt, rowstart, bsum, N);
  k_scan_sums<<<1,256,0,stream>>>(bsum, nb);
  k_scan_add<<<nb,256,0,stream>>>(rowstart, bsum, N, E);
  k_place<<<(E+255)/256,256,0,stream>>>(ei, rowstart, rank, csr16, E);
  k_prep_wt_gat<<<192,256,0,stream>>>(gatW, wt_gat);
  k_prep_wt_gatt<<<48,128,0,stream>>>(gatW, attS, attD, wt_gat);
  k_prep_wt_qkvs<<<256,256,0,stream>>>(Wq, Wk, Wv, Wsk, bq, bk, bv, bsk, wt_qkvs, bias512);

  int gemm_grid = (N+63)/64;
  for (int l=0;l<3;++l){
    k_gemm_mfma<1,1><<<gemm_grid,256,0,stream>>>(hb, wt_gat + (size_t)l*18432, nullptr,
                                                 hw8, nullptr, nullptr, a_sd, N);
    k_gat_agg<<<(N+3)/4,256,0,stream>>>(rowstart, csr16, hw8, a_sd, gatB + l*128, hb, N);
  }

  k_gemm_mfma<4,2><<<gemm_grid,256,0,stream>>>(hb, wt_qkvs, bias512, yq, ykv, ysk, nullptr, N);
  k_trans_agg<<<(N+3)/4,256,0,stream>>>(rowstart, csr16, yq, ykv, ysk, lng, lnb, hb, N);

  k_pool<<<G,64,0,stream>>>(hb, batch, out, N, G);
}

// Round 7
// 407.969 us; speedup vs baseline: 4.0522x; 1.1090x over previous
//
#include <hip/hip_runtime.h>
#include <hip/hip_bf16.h>

typedef unsigned int uint;
typedef unsigned short ushort;
typedef __attribute__((ext_vector_type(8))) short bf16x8;
typedef __attribute__((ext_vector_type(4))) float f32x4;
typedef __attribute__((ext_vector_type(2))) float f32x2;

__device__ __forceinline__ float2 bf2_to_f2(uint u){
  union {unsigned int i; float f;} a,b;
  a.i = (u & 0xffffu) << 16;
  b.i = u & 0xffff0000u;
  return make_float2(a.f, b.f);
}
__device__ __forceinline__ float b2f(ushort u){
  union{uint i; float f;} x; x.i = (uint)u << 16; return x.f;
}
__device__ __forceinline__ ushort bf16bits(float f){
  union{ __hip_bfloat16 h; ushort u;} x; x.h = __float2bfloat16(f); return x.u;
}
__device__ __forceinline__ uint pack_bf2(float x, float y){
  return ((uint)bf16bits(y)<<16) | (uint)bf16bits(x);
}

// ---------------- init / CSR build ----------------

__global__ void k_init_h(const int* __restrict__ xn, const float* __restrict__ table,
                         ushort* __restrict__ hb, int n){
  int gid = blockIdx.x*blockDim.x + threadIdx.x;
  if (gid >= n*64) return;
  int node = gid >> 6, lp = gid & 63;
  int x0 = xn[2*node];
  int x1 = xn[2*node+1]; x1 = x1<0?0:(x1>19?19:x1);
  const float* tr = table + (size_t)(x0*20+x1)*128 + lp*2;
  reinterpret_cast<uint*>(hb)[(size_t)node*64 + lp] = pack_bf2(tr[0], tr[1]);
}

// rank[e] = arrival index within dst row; cnt accumulates degree (real edges only)
__global__ void k_rank(const int* __restrict__ ei, int* __restrict__ cnt,
                       int* __restrict__ rank, int E){
  int e = blockIdx.x*blockDim.x + threadIdx.x;
  if (e >= E) return;
  rank[e] = atomicAdd(&cnt[ei[E+e]], 1);
}

__global__ __launch_bounds__(256) void k_scan_block(const int* __restrict__ deg, int* __restrict__ rowstart,
                                                    int* __restrict__ bsum, int n){
  int tid = threadIdx.x;
  int gid = blockIdx.x*256 + tid;
  int lane = tid & 63, wv = tid >> 6;
  int v = (gid < n) ? deg[gid] : 0;
  int x = v;
  #pragma unroll
  for (int off=1; off<64; off<<=1){
    int t = __shfl_up(x, off);
    if (lane >= off) x += t;
  }
  __shared__ int wsum[4], woff[4];
  if (lane==63) wsum[wv] = x;
  __syncthreads();
  if (tid==0){
    int r = 0;
    for (int i=0;i<4;++i){ woff[i]=r; r += wsum[i]; }
    bsum[blockIdx.x] = r;
  }
  __syncthreads();
  if (gid < n) rowstart[gid] = x + woff[wv] - v;
}

__global__ __launch_bounds__(256) void k_scan_sums(int* __restrict__ bsum, int nb){
  int tid = threadIdx.x;
  int lane = tid&63, wv = tid>>6;
  int v = (tid<nb)?bsum[tid]:0;
  int x = v;
  #pragma unroll
  for (int off=1;off<64;off<<=1){ int t=__shfl_up(x,off); if(lane>=off) x+=t; }
  __shared__ int wsum[4], woff[4];
  if (lane==63) wsum[wv]=x;
  __syncthreads();
  if (tid==0){ int r=0; for(int i=0;i<4;++i){woff[i]=r;r+=wsum[i];} }
  __syncthreads();
  if (tid<nb) bsum[tid] = x + woff[wv] - v;
}

__global__ void k_scan_add(int* __restrict__ rowstart, const int* __restrict__ bsum, int n, int total){
  int gid = blockIdx.x*256 + threadIdx.x;
  if (gid < n) rowstart[gid] += bsum[blockIdx.x];
  if (gid == 0) rowstart[n] = total;
}

__global__ void k_place(const int* __restrict__ ei, const int* __restrict__ rowstart,
                        const int* __restrict__ rank, ushort* __restrict__ csr16, int E){
  int e = blockIdx.x*blockDim.x + threadIdx.x;
  if (e >= E) return;
  csr16[rowstart[ei[E+e]] + rank[e]] = (ushort)ei[e];
}

// ---------------- fused weight/table prep ----------------
// blocks [0,192): gat W transpose; [192,216): gat att cols; [216,472): qkvs; [472,562): h0 table
__global__ __launch_bounds__(256) void k_prep_all(
    const float* __restrict__ gatW, const float* __restrict__ attS, const float* __restrict__ attD,
    const float* __restrict__ Wq, const float* __restrict__ Wk,
    const float* __restrict__ Wv, const float* __restrict__ Ws,
    const float* __restrict__ bq, const float* __restrict__ bk,
    const float* __restrict__ bv, const float* __restrict__ bs,
    const float* __restrict__ emb, const float* __restrict__ demb,
    const float* __restrict__ projW, const float* __restrict__ projB,
    ushort* __restrict__ wt_gat, ushort* __restrict__ wt_qkvs,
    float* __restrict__ bias512, float* __restrict__ table){
  int blk = blockIdx.x, t = threadIdx.x;
  if (blk < 192){
    int i = blk*256 + t;      // < 3*128*128
    int l = i >> 14, rem = i & 16383, c = rem >> 7, k = rem & 127;
    wt_gat[(size_t)l*18432 + c*128 + k] = bf16bits(gatW[l*16384 + k*128 + c]);
  } else if (blk < 216){
    int idx = (blk-192)*256 + t;   // < 6144
    int l = idx >> 11, i16 = (idx >> 7) & 15, k = idx & 127;
    float acc = 0.f;
    if (i16 < 8){
      int sd = i16 >> 2, hh = i16 & 3;
      const float* att = (sd ? attD : attS) + l*128 + hh*32;
      #pragma unroll 8
      for (int c=0;c<32;++c) acc += gatW[l*16384 + k*128 + hh*32 + c] * att[c];
    }
    wt_gat[(size_t)l*18432 + (128+i16)*128 + k] = bf16bits(acc);
  } else if (blk < 472){
    int i = (blk-216)*256 + t;   // < 512*128
    int c = i >> 7, k = i & 127;
    const float* W; const float* B; int sc; float scale = 1.f;
    if (c < 128){ W = Wq; B = bq; sc = c; scale = 0.011048543456039805f; } // 1/(sqrt(32)*16)
    else if (c < 384){
      int ct = c >> 7, within = c & 127, cf = within >> 4, cl = within & 15;
      int m = cl + 16*((ct-1)*2 + (cf>>2));
      int wn = cf & 3;
      if (wn < 2){ W = Wk; B = bk; sc = 2*m + wn; }
      else       { W = Wv; B = bv; sc = 2*m + wn - 2; }
    } else { W = Ws; B = bs; sc = c - 384; }
    wt_qkvs[c*128 + k] = bf16bits(W[k*128 + sc] * scale);
    if (k == 0) bias512[c] = B[sc] * scale;
  } else {
    int idx = (blk-472)*256 + t;   // < 180*128
    int combo = idx >> 7, d = idx & 127;
    int a = combo/20, b = combo - a*20;
    float acc = projB[d];
    #pragma unroll 8
    for (int i=0;i<32;++i) acc += emb[a*32+i]*projW[i*128+d];
    #pragma unroll 8
    for (int i=0;i<32;++i) acc += demb[b*32+i]*projW[(32+i)*128+d];
    table[combo*128+d] = acc;
  }
}

// ---------------- MFMA GEMM ----------------
// MODE 1: CT=1, 144 cols: cf0..7 -> fp8 messages (x16, permuted: byte cl*8+cf = col cf*16+cl);
//         cf8 -> a_sd[node][8] (cl<8).
// MODE 2: CT=4, 128 cols/tile: ct0 -> q bf16, ct1/2 -> kv fp8 quads, ct3 -> skip bf16.
template<int CT, int MODE>
__global__ __launch_bounds__(256) void k_gemm_mfma(const ushort* __restrict__ X,
        const ushort* __restrict__ Wt, const float* __restrict__ bias,
        void* __restrict__ Yq, uint* __restrict__ Ykv, ushort* __restrict__ Ysk,
        float* __restrict__ Asd, int n){
  constexpr int COLS = (MODE==1) ? 144 : 128;
  constexpr int NCF  = COLS/16;
  __shared__ ushort wl[COLS*136];
  const int t = threadIdx.x;
  const int w = t >> 6, lane = t & 63;
  const int cl = lane & 15, khi = lane >> 4;
  const int rbase = blockIdx.x*64;

  int arow = rbase + w*16 + cl; if (arow >= n) arow = n-1;
  const bf16x8* Xr = reinterpret_cast<const bf16x8*>(X + (size_t)arow*128);
  bf16x8 a0 = Xr[0+khi], a1 = Xr[4+khi], a2 = Xr[8+khi], a3 = Xr[12+khi];

  for (int ct=0; ct<CT; ++ct){
    const ushort* wsrc = Wt + (size_t)ct*16384;
    __syncthreads();
    for (int idx = t; idx < COLS*2; idx += 256){
      int col = idx >> 1, k0 = (idx & 1)*64;
      const bf16x8* src = reinterpret_cast<const bf16x8*>(wsrc + (size_t)col*128 + k0);
      bf16x8* dst = reinterpret_cast<bf16x8*>(wl + col*136 + k0);
      #pragma unroll
      for (int i=0;i<8;++i) dst[i] = src[i];
    }
    __syncthreads();

    f32x4 acc[NCF];
    #pragma unroll
    for (int cf=0;cf<NCF;++cf) acc[cf] = f32x4{0.f,0.f,0.f,0.f};

    #pragma unroll
    for (int ks=0; ks<4; ++ks){
      bf16x8 av = (ks==0)?a0:(ks==1)?a1:(ks==2)?a2:a3;
      #pragma unroll
      for (int cf=0; cf<NCF; ++cf){
        bf16x8 bv = *reinterpret_cast<const bf16x8*>(wl + (cf*16+cl)*136 + ks*32 + khi*8);
        acc[cf] = __builtin_amdgcn_mfma_f32_16x16x32_bf16(av, bv, acc[cf], 0, 0, 0);
      }
    }

    #pragma unroll
    for (int j=0;j<4;++j){
      int node = rbase + w*16 + khi*4 + j;
      if (node < n){
        if (MODE==1){
          unsigned char* Y8 = (unsigned char*)Yq;
          float f0 = acc[0][j]*16.f, f1 = acc[1][j]*16.f, f2 = acc[2][j]*16.f, f3 = acc[3][j]*16.f;
          float f4 = acc[4][j]*16.f, f5 = acc[5][j]*16.f, f6 = acc[6][j]*16.f, f7 = acc[7][j]*16.f;
          int d0 = __builtin_amdgcn_cvt_pk_fp8_f32(f0, f1, 0, false);
          d0     = __builtin_amdgcn_cvt_pk_fp8_f32(f2, f3, d0, true);
          int d1 = __builtin_amdgcn_cvt_pk_fp8_f32(f4, f5, 0, false);
          d1     = __builtin_amdgcn_cvt_pk_fp8_f32(f6, f7, d1, true);
          *reinterpret_cast<uint2*>(Y8 + (size_t)node*128 + cl*8) = make_uint2((uint)d0, (uint)d1);
          if (cl < 8) Asd[(size_t)node*8 + cl] = acc[8][j];
        } else {
          if (ct == 0 || ct == 3){
            ushort* Y = (ct == 0) ? (ushort*)Yq : Ysk;
            ushort* yr = Y + (size_t)node*128 + cl;
            #pragma unroll
            for (int cf=0;cf<8;++cf)
              yr[cf*16] = bf16bits(acc[cf][j] + bias[ct*128 + cf*16 + cl]);
          } else {
            #pragma unroll
            for (int g=0; g<2; ++g){
              float f0 = (acc[g*4+0][j] + bias[ct*128 + (g*4+0)*16 + cl])*16.f;
              float f1 = (acc[g*4+1][j] + bias[ct*128 + (g*4+1)*16 + cl])*16.f;
              float f2 = (acc[g*4+2][j] + bias[ct*128 + (g*4+2)*16 + cl])*16.f;
              float f3 = (acc[g*4+3][j] + bias[ct*128 + (g*4+3)*16 + cl])*16.f;
              int d = __builtin_amdgcn_cvt_pk_fp8_f32(f0, f1, 0, false);
              d     = __builtin_amdgcn_cvt_pk_fp8_f32(f2, f3, d, true);
              int m = cl + 16*((ct-1)*2 + g);
              Ykv[(size_t)node*64 + m] = (uint)d;
            }
          }
        }
      }
    }
  }
}

// ---------------- GAT aggregate: half-wave per edge, dword gathers ----------------
// lane l: b=l&31, half=l>>5. Lane's dword covers cols cf=(b&1?4:0)+t (t=0..3), cl=b>>1,
// i.e. heads h0=(b&1)*2 and h0+1. Halves process alternating edges; combine via shfl_xor(32).
__global__ __launch_bounds__(256) void k_gat_agg(const int* __restrict__ rowstart, const ushort* __restrict__ csr16,
              const unsigned char* __restrict__ hw8, const float* __restrict__ a_sd,
              const float* __restrict__ bias, ushort* __restrict__ hb, int n){
  __shared__ float4 lw[4][64];
  __shared__ ushort lsrc[4][64];
  int wv = threadIdx.x >> 6, l = threadIdx.x & 63;
  int node = blockIdx.x*4 + wv;
  if (node >= n) return;
  int b = l & 31, half = l >> 5;
  int h0 = (b & 1) * 2;
  int cl = b >> 1;
  int start = rowstart[node], end = rowstart[node+1];
  float4 ad4 = *reinterpret_cast<const float4*>(a_sd + (size_t)node*8 + 4);
  const uint* rows32 = reinterpret_cast<const uint*>(hw8);

  float a0=0.f,a1=0.f,a2=0.f,a3=0.f,sA=0.f,sB=0.f;
  if (half == 0){
    // self-loop handled once (not in CSR)
    float adA = (h0==0) ? ad4.x : ad4.z;
    float adB = (h0==0) ? ad4.y : ad4.w;
    float scA = a_sd[(size_t)node*8 + h0]     + adA; scA = fmaxf(scA, 0.2f*scA);
    float scB = a_sd[(size_t)node*8 + h0 + 1] + adB; scB = fmaxf(scB, 0.2f*scB);
    float wA = __expf(fminf(scA,30.f));
    float wB = __expf(fminf(scB,30.f));
    uint u = rows32[(size_t)node*32 + b];
    f32x2 flo = __builtin_amdgcn_cvt_pk_f32_fp8((int)u, false);
    f32x2 fhi = __builtin_amdgcn_cvt_pk_f32_fp8((int)u, true);
    sA = wA; sB = wB;
    a0 = wA*flo.x; a1 = wA*flo.y; a2 = wB*fhi.x; a3 = wB*fhi.y;
  }

  const float* lwf = reinterpret_cast<const float*>(&lw[wv][0]);
  for (int base = start; base < end; base += 64){
    int len = end - base; if (len > 64) len = 64;
    if (l < len){
      int sv = csr16[base + l];
      lsrc[wv][l] = (ushort)sv;
      float4 a4 = *reinterpret_cast<const float4*>(a_sd + (size_t)sv*8);
      float s0 = a4.x + ad4.x; s0 = fmaxf(s0, 0.2f*s0);
      float s1 = a4.y + ad4.y; s1 = fmaxf(s1, 0.2f*s1);
      float s2 = a4.z + ad4.z; s2 = fmaxf(s2, 0.2f*s2);
      float s3 = a4.w + ad4.w; s3 = fmaxf(s3, 0.2f*s3);
      float4 w4;
      w4.x = __expf(fminf(s0,30.f));
      w4.y = __expf(fminf(s1,30.f));
      w4.z = __expf(fminf(s2,30.f));
      w4.w = __expf(fminf(s3,30.f));
      lw[wv][l] = w4;
    }
    int p = half;
    for (; p+6 < len; p += 8){
      int e0 = lsrc[wv][p], e1 = lsrc[wv][p+2], e2 = lsrc[wv][p+4], e3 = lsrc[wv][p+6];
      float2 w0 = *reinterpret_cast<const float2*>(lwf + p*4 + h0);
      float2 w1 = *reinterpret_cast<const float2*>(lwf + (p+2)*4 + h0);
      float2 w2 = *reinterpret_cast<const float2*>(lwf + (p+4)*4 + h0);
      float2 w3 = *reinterpret_cast<const float2*>(lwf + (p+6)*4 + h0);
      uint u0 = rows32[(size_t)e0*32 + b];
      uint u1 = rows32[(size_t)e1*32 + b];
      uint u2 = rows32[(size_t)e2*32 + b];
      uint u3 = rows32[(size_t)e3*32 + b];
      f32x2 f;
      f = __builtin_amdgcn_cvt_pk_f32_fp8((int)u0, false); a0 += w0.x*f.x; a1 += w0.x*f.y;
      f = __builtin_amdgcn_cvt_pk_f32_fp8((int)u0, true);  a2 += w0.y*f.x; a3 += w0.y*f.y;
      f = __builtin_amdgcn_cvt_pk_f32_fp8((int)u1, false); a0 += w1.x*f.x; a1 += w1.x*f.y;
      f = __builtin_amdgcn_cvt_pk_f32_fp8((int)u1, true);  a2 += w1.y*f.x; a3 += w1.y*f.y;
      f = __builtin_amdgcn_cvt_pk_f32_fp8((int)u2, false); a0 += w2.x*f.x; a1 += w2.x*f.y;
      f = __builtin_amdgcn_cvt_pk_f32_fp8((int)u2, true);  a2 += w2.y*f.x; a3 += w2.y*f.y;
      f = __builtin_amdgcn_cvt_pk_f32_fp8((int)u3, false); a0 += w3.x*f.x; a1 += w3.x*f.y;
      f = __builtin_amdgcn_cvt_pk_f32_fp8((int)u3, true);  a2 += w3.y*f.x; a3 += w3.y*f.y;
      sA += (w0.x+w1.x)+(w2.x+w3.x);
      sB += (w0.y+w1.y)+(w2.y+w3.y);
    }
    for (; p < len; p += 2){
      int e0 = lsrc[wv][p];
      float2 w0 = *reinterpret_cast<const float2*>(lwf + p*4 + h0);
      uint u0 = rows32[(size_t)e0*32 + b];
      f32x2 f;
      f = __builtin_amdgcn_cvt_pk_f32_fp8((int)u0, false); a0 += w0.x*f.x; a1 += w0.x*f.y;
      f = __builtin_amdgcn_cvt_pk_f32_fp8((int)u0, true);  a2 += w0.y*f.x; a3 += w0.y*f.y;
      sA += w0.x; sB += w0.y;
    }
  }
  // combine halves
  a0 += __shfl_xor(a0,32); a1 += __shfl_xor(a1,32);
  a2 += __shfl_xor(a2,32); a3 += __shfl_xor(a3,32);
  sA += __shfl_xor(sA,32); sB += __shfl_xor(sB,32);
  float invA = (1.f/16.f)/(sA + 1e-16f);
  float invB = (1.f/16.f)/(sB + 1e-16f);
  // half 0 writes cols t=0,1 (head h0); half 1 writes t=2,3 (head h0+1)
  float accx = half ? a2 : a0;
  float accy = half ? a3 : a1;
  float inv  = half ? invB : invA;
  int c0 = (h0*2 + half*2)*16 + cl;
  int c1 = c0 + 16;
  float o0 = accx*inv + bias[c0]; o0 = o0 > 0.f ? o0 : (__expf(o0)-1.f);
  float o1 = accy*inv + bias[c1]; o1 = o1 > 0.f ? o1 : (__expf(o1)-1.f);
  float hx = b2f(hb[(size_t)node*128 + c0]) + o0;
  float hy = b2f(hb[(size_t)node*128 + c1]) + o1;
  hb[(size_t)node*128 + c0] = bf16bits(hx);
  hb[(size_t)node*128 + c1] = bf16bits(hy);
}

// ---------------- transformer aggregate + fused layernorm (8-edge unroll) ----------------
__global__ __launch_bounds__(256) void k_trans_agg(const int* __restrict__ rowstart, const ushort* __restrict__ csr16,
              const ushort* __restrict__ yq, const uint* __restrict__ ykv,
              const ushort* __restrict__ ysk, const float* __restrict__ lng,
              const float* __restrict__ lnb, ushort* __restrict__ hb, int n){
  int wv = threadIdx.x>>6, lane = threadIdx.x&63;
  int node = blockIdx.x*4 + wv;
  if (node >= n) return;
  int li = lane & 15;
  bool odd1 = li & 1, odd2 = li & 2;
  int lbase = lane & 48;
  const uint* q32 = reinterpret_cast<const uint*>(yq);
  const uint* s32 = reinterpret_cast<const uint*>(ysk);
  uint* h32 = reinterpret_cast<uint*>(hb);
  float2 q2 = bf2_to_f2(q32[(size_t)node*64 + lane]);   // q pre-scaled by 1/(sqrt(32)*16)
  int start = rowstart[node], end = rowstart[node+1];
  float s = 0.f, s_tail = 0.f, ax = 0.f, ay = 0.f;
  int p = start;
  for (; p+7 < end; p += 8){
    int i0 = csr16[p],   i1 = csr16[p+1], i2 = csr16[p+2], i3 = csr16[p+3];
    int i4 = csr16[p+4], i5 = csr16[p+5], i6 = csr16[p+6], i7 = csr16[p+7];
    uint u0 = ykv[(size_t)i0*64 + lane];
    uint u1 = ykv[(size_t)i1*64 + lane];
    uint u2 = ykv[(size_t)i2*64 + lane];
    uint u3 = ykv[(size_t)i3*64 + lane];
    uint u4 = ykv[(size_t)i4*64 + lane];
    uint u5 = ykv[(size_t)i5*64 + lane];
    uint u6 = ykv[(size_t)i6*64 + lane];
    uint u7 = ykv[(size_t)i7*64 + lane];
    // group A scores
    f32x2 k0 = __builtin_amdgcn_cvt_pk_f32_fp8((int)u0, false);
    f32x2 k1 = __builtin_amdgcn_cvt_pk_f32_fp8((int)u1, false);
    f32x2 k2 = __builtin_amdgcn_cvt_pk_f32_fp8((int)u2, false);
    f32x2 k3 = __builtin_amdgcn_cvt_pk_f32_fp8((int)u3, false);
    float p0 = q2.x*k0.x + q2.y*k0.y;
    float p1 = q2.x*k1.x + q2.y*k1.y;
    float p2 = q2.x*k2.x + q2.y*k2.y;
    float p3 = q2.x*k3.x + q2.y*k3.y;
    float aA = (odd1 ? p1 : p0) + __shfl_xor(odd1 ? p0 : p1, 1);
    float bA = (odd1 ? p3 : p2) + __shfl_xor(odd1 ? p2 : p3, 1);
    float cA = (odd2 ? bA : aA) + __shfl_xor(odd2 ? aA : bA, 2);
    cA += __shfl_xor(cA, 4);
    cA += __shfl_xor(cA, 8);
    float wA = __expf(fminf(cA, 30.f));
    // group B scores
    f32x2 k4 = __builtin_amdgcn_cvt_pk_f32_fp8((int)u4, false);
    f32x2 k5 = __builtin_amdgcn_cvt_pk_f32_fp8((int)u5, false);
    f32x2 k6 = __builtin_amdgcn_cvt_pk_f32_fp8((int)u6, false);
    f32x2 k7 = __builtin_amdgcn_cvt_pk_f32_fp8((int)u7, false);
    float p4 = q2.x*k4.x + q2.y*k4.y;
    float p5 = q2.x*k5.x + q2.y*k5.y;
    float p6 = q2.x*k6.x + q2.y*k6.y;
    float p7 = q2.x*k7.x + q2.y*k7.y;
    float aB = (odd1 ? p5 : p4) + __shfl_xor(odd1 ? p4 : p5, 1);
    float bB = (odd1 ? p7 : p6) + __shfl_xor(odd1 ? p6 : p7, 1);
    float cB = (odd2 ? bB : aB) + __shfl_xor(odd2 ? aB : bB, 2);
    cB += __shfl_xor(cB, 4);
    cB += __shfl_xor(cB, 8);
    float wB = __expf(fminf(cB, 30.f));
    s += wA + wB;
    float w0 = __shfl(wA, lbase);
    float w1 = __shfl(wA, lbase|1);
    float w2 = __shfl(wA, lbase|2);
    float w3 = __shfl(wA, lbase|3);
    float w4 = __shfl(wB, lbase);
    float w5 = __shfl(wB, lbase|1);
    float w6 = __shfl(wB, lbase|2);
    float w7 = __shfl(wB, lbase|3);
    f32x2 v0 = __builtin_amdgcn_cvt_pk_f32_fp8((int)u0, true);
    f32x2 v1 = __builtin_amdgcn_cvt_pk_f32_fp8((int)u1, true);
    f32x2 v2 = __builtin_amdgcn_cvt_pk_f32_fp8((int)u2, true);
    f32x2 v3 = __builtin_amdgcn_cvt_pk_f32_fp8((int)u3, true);
    f32x2 v4 = __builtin_amdgcn_cvt_pk_f32_fp8((int)u4, true);
    f32x2 v5 = __builtin_amdgcn_cvt_pk_f32_fp8((int)u5, true);
    f32x2 v6 = __builtin_amdgcn_cvt_pk_f32_fp8((int)u6, true);
    f32x2 v7 = __builtin_amdgcn_cvt_pk_f32_fp8((int)u7, true);
    ax += w0*v0.x + w1*v1.x + w2*v2.x + w3*v3.x
        + w4*v4.x + w5*v5.x + w6*v6.x + w7*v7.x;
    ay += w0*v0.y + w1*v1.y + w2*v2.y + w3*v3.y
        + w4*v4.y + w5*v5.y + w6*v6.y + w7*v7.y;
  }
  for (; p+3 < end; p += 4){
    int i0 = csr16[p], i1 = csr16[p+1], i2 = csr16[p+2], i3 = csr16[p+3];
    uint u0 = ykv[(size_t)i0*64 + lane];
    uint u1 = ykv[(size_t)i1*64 + lane];
    uint u2 = ykv[(size_t)i2*64 + lane];
    uint u3 = ykv[(size_t)i3*64 + lane];
    f32x2 k0 = __builtin_amdgcn_cvt_pk_f32_fp8((int)u0, false);
    f32x2 k1 = __builtin_amdgcn_cvt_pk_f32_fp8((int)u1, false);
    f32x2 k2 = __builtin_amdgcn_cvt_pk_f32_fp8((int)u2, false);
    f32x2 k3 = __builtin_amdgcn_cvt_pk_f32_fp8((int)u3, false);
    float p0 = q2.x*k0.x + q2.y*k0.y;
    float p1 = q2.x*k1.x + q2.y*k1.y;
    float p2 = q2.x*k2.x + q2.y*k2.y;
    float p3 = q2.x*k3.x + q2.y*k3.y;
    float aA = (odd1 ? p1 : p0) + __shfl_xor(odd1 ? p0 : p1, 1);
    float bA = (odd1 ? p3 : p2) + __shfl_xor(odd1 ? p2 : p3, 1);
    float cA = (odd2 ? bA : aA) + __shfl_xor(odd2 ? aA : bA, 2);
    cA += __shfl_xor(cA, 4);
    cA += __shfl_xor(cA, 8);
    float w = __expf(fminf(cA, 30.f));
    s += w;
    float w0 = __shfl(w, lbase);
    float w1 = __shfl(w, lbase|1);
    float w2 = __shfl(w, lbase|2);
    float w3 = __shfl(w, lbase|3);
    f32x2 v0 = __builtin_amdgcn_cvt_pk_f32_fp8((int)u0, true);
    f32x2 v1 = __builtin_amdgcn_cvt_pk_f32_fp8((int)u1, true);
    f32x2 v2 = __builtin_amdgcn_cvt_pk_f32_fp8((int)u2, true);
    f32x2 v3 = __builtin_amdgcn_cvt_pk_f32_fp8((int)u3, true);
    ax += w0*v0.x + w1*v1.x + w2*v2.x + w3*v3.x;
    ay += w0*v0.y + w1*v1.y + w2*v2.y + w3*v3.y;
  }
  for (; p < end; ++p){
    int idx = csr16[p];
    uint u = ykv[(size_t)idx*64 + lane];
    f32x2 k2 = __builtin_amdgcn_cvt_pk_f32_fp8((int)u, false);
    float pr = q2.x*k2.x + q2.y*k2.y;
    pr += __shfl_xor(pr,1); pr += __shfl_xor(pr,2);
    pr += __shfl_xor(pr,4); pr += __shfl_xor(pr,8);
    float wt = __expf(fminf(pr, 30.f));
    f32x2 v2 = __builtin_amdgcn_cvt_pk_f32_fp8((int)u, true);
    s_tail += wt; ax += wt*v2.x; ay += wt*v2.y;
  }
  s += __shfl_xor(s, 1);
  s += __shfl_xor(s, 2);
  s += s_tail;
  float inv = (1.f/16.f)/(s + 1e-16f);       // fold out v's x16 scale
  int d = lane*2;
  float2 sk = bf2_to_f2(s32[(size_t)node*64 + lane]);
  float tx = ax*inv + sk.x;
  float ty = ay*inv + sk.y;
  tx = tx>0.f?tx:(__expf(tx)-1.f);
  ty = ty>0.f?ty:(__expf(ty)-1.f);
  float2 hp = bf2_to_f2(h32[(size_t)node*64 + lane]);
  hp.x += tx; hp.y += ty;
  // fused layernorm
  float sm = hp.x + hp.y;
  #pragma unroll
  for (int m=1;m<64;m<<=1) sm += __shfl_xor(sm,m);
  float mu = sm * (1.f/128.f);
  float dx = hp.x-mu, dy = hp.y-mu;
  float vs = dx*dx + dy*dy;
  #pragma unroll
  for (int m=1;m<64;m<<=1) vs += __shfl_xor(vs,m);
  float r = rsqrtf(vs*(1.f/128.f) + 1e-5f);
  float2 gg = *reinterpret_cast<const float2*>(lng+d);
  float2 bb = *reinterpret_cast<const float2*>(lnb+d);
  h32[(size_t)node*64 + lane] = pack_bf2(dx*r*gg.x + bb.x, dy*r*gg.y + bb.y);
}

// ---------------- pooling (fused bounds search) ----------------
__global__ void k_pool(const ushort* __restrict__ hb, const int* __restrict__ batch,
                       float* __restrict__ out, int n, int G){
  int g = blockIdx.x, t = threadIdx.x;   // 64 threads
  int lo=0, hi=n;
  while (lo<hi){ int m=(lo+hi)>>1; if (batch[m] < g) lo=m+1; else hi=m; }
  int s = lo;
  lo=s; hi=n;
  while (lo<hi){ int m=(lo+hi)>>1; if (batch[m] < g+1) lo=m+1; else hi=m; }
  int e = lo;
  const uint* rows = reinterpret_cast<const uint*>(hb);
  float ax=0.f, ay=0.f;
  for (int i=s;i<e;++i){
    float2 f = bf2_to_f2(rows[(size_t)i*64 + t]);
    ax += f.x; ay += f.y;
  }
  float invc = 1.f / fmaxf((float)(e-s), 1.f);
  out[(size_t)g*128 + 2*t]   = ax*invc;
  out[(size_t)g*128 + 2*t+1] = ay*invc;
}

// ---------------- launch ----------------
extern "C" void kernel_launch(void* const* d_in, const int* in_sizes, int n_in,
                              void* d_out, int out_size, void* d_ws, size_t ws_size,
                              hipStream_t stream){
  const int* xn    = (const int*)d_in[0];
  const int* ei    = (const int*)d_in[1];
  const int* batch = (const int*)d_in[2];
  const float* emb  = (const float*)d_in[4];
  const float* demb = (const float*)d_in[5];
  const float* projW= (const float*)d_in[6];
  const float* projB= (const float*)d_in[7];
  const float* gatW = (const float*)d_in[8];
  const float* attS = (const float*)d_in[9];
  const float* attD = (const float*)d_in[10];
  const float* gatB = (const float*)d_in[11];
  const float* Wq = (const float*)d_in[12];
  const float* bq = (const float*)d_in[13];
  const float* Wk = (const float*)d_in[14];
  const float* bk = (const float*)d_in[15];
  const float* Wv = (const float*)d_in[16];
  const float* bv = (const float*)d_in[17];
  const float* Wsk= (const float*)d_in[18];
  const float* bsk= (const float*)d_in[19];
  const float* lng= (const float*)d_in[20];
  const float* lnb= (const float*)d_in[21];
  float* out = (float*)d_out;

  int N = in_sizes[0]/2;
  int E = in_sizes[1]/2;
  int G = out_size/128;

  char* w = (char*)d_ws;
  size_t off = 0;
  auto alloc = [&](size_t bytes)->char*{ char* p = w+off; off += (bytes + 255) & ~(size_t)255; return p; };
  ushort* hb   = (ushort*)alloc((size_t)N*128*2);   // h lives only as bf16
  ushort* yq   = (ushort*)alloc((size_t)N*128*2);   // q bf16; fp8 hw aliases its front half
  uint*   ykv  = (uint*)  alloc((size_t)N*64*4);    // fp8 kv quads
  ushort* ysk  = (ushort*)alloc((size_t)N*128*2);   // skip bf16
  unsigned char* hw8 = (unsigned char*)yq;
  float* a_sd = (float*)alloc((size_t)N*8*4);       // [node][a_s h0..3 | a_d h0..3]
  int* cnt    = (int*)alloc((size_t)N*4);
  int* rowstart=(int*)alloc((size_t)(N+1)*4);
  int* rank   = (int*)alloc((size_t)E*4);
  ushort* csr16 = (ushort*)alloc((size_t)E*2);
  int* bsum   = (int*)alloc(4096);
  float* table= (float*)alloc(180*128*4);
  ushort* wt_gat  = (ushort*)alloc((size_t)3*144*128*2);
  ushort* wt_qkvs = (ushort*)alloc((size_t)512*128*2);
  float* bias512  = (float*)alloc(512*4);
  (void)ws_size; (void)n_in;

  int nb = (N+255)/256;

  hipMemsetAsync(cnt, 0, (size_t)N*4, stream);
  k_prep_all<<<562,256,0,stream>>>(gatW, attS, attD, Wq, Wk, Wv, Wsk,
                                   bq, bk, bv, bsk, emb, demb, projW, projB,
                                   wt_gat, wt_qkvs, bias512, table);
  k_init_h<<<(N*64+255)/256,256,0,stream>>>(xn, table, hb, N);
  k_rank<<<(E+255)/256,256,0,stream>>>(ei, cnt, rank, E);
  k_scan_block<<<nb,256,0,stream>>>(cnt, rowstart, bsum, N);
  k_scan_sums<<<1,256,0,stream>>>(bsum, nb);
  k_scan_add<<<nb,256,0,stream>>>(rowstart, bsum, N, E);
  k_place<<<(E+255)/256,256,0,stream>>>(ei, rowstart, rank, csr16, E);

  int gemm_grid = (N+63)/64;
  for (int l=0;l<3;++l){
    k_gemm_mfma<1,1><<<gemm_grid,256,0,stream>>>(hb, wt_gat + (size_t)l*18432, nullptr,
                                                 hw8, nullptr, nullptr, a_sd, N);
    k_gat_agg<<<(N+3)/4,256,0,stream>>>(rowstart, csr16, hw8, a_sd, gatB + l*128, hb, N);
  }

  k_gemm_mfma<4,2><<<gemm_grid,256,0,stream>>>(hb, wt_qkvs, bias512, yq, ykv, ysk, nullptr, N);
  k_trans_agg<<<(N+3)/4,256,0,stream>>>(rowstart, csr16, yq, ykv, ysk, lng, lnb, hb, N);

  k_pool<<<G,64,0,stream>>>(hb, batch, out, N, G);
}